// Round 9
// baseline (154.146 us; speedup 1.0000x reference)
//
#include <hip/hip_runtime.h>
#include <stdint.h>

#define D_MODEL 1024
#define NHEADS  16
#define DEPTH   64
#define BATCH   2
#define SEQ     2048
#define M_TOK   (BATCH*SEQ)   // 4096

typedef __attribute__((ext_vector_type(8)))  short short8;
typedef __attribute__((ext_vector_type(4)))  float f32x4;
typedef __attribute__((ext_vector_type(16))) float f32x16;
typedef __attribute__((ext_vector_type(4)))  unsigned int uint4v;

__device__ __forceinline__ unsigned short f2bf(float f) {
  unsigned int u = __float_as_uint(f);
  u += 0x7fffu + ((u >> 16) & 1u);
  return (unsigned short)(u >> 16);
}

__device__ __forceinline__ unsigned int cvt_pk_bf16(float lo, float hi) {
  unsigned int r;
  asm("v_cvt_pk_bf16_f32 %0, %1, %2" : "=v"(r) : "v"(lo), "v"(hi));
  return r;
}

__device__ __forceinline__ void gload_lds16(const unsigned short* g, unsigned short* l) {
  __builtin_amdgcn_global_load_lds((const __attribute__((address_space(1))) void*)g,
                                   (__attribute__((address_space(3))) void*)l, 16, 0, 0);
}

// ---------------- fp32 -> bf16 elementwise (x) ----------------
__global__ void mha_cvt_bf16(const float* __restrict__ in, unsigned short* __restrict__ out) {
  int i = (blockIdx.x * 256 + threadIdx.x) * 8;
  float4 a = *(const float4*)(in + i);
  float4 b = *(const float4*)(in + i + 4);
  uint4 r;
  r.x = (unsigned)f2bf(a.x) | ((unsigned)f2bf(a.y) << 16);
  r.y = (unsigned)f2bf(a.z) | ((unsigned)f2bf(a.w) << 16);
  r.z = (unsigned)f2bf(b.x) | ((unsigned)f2bf(b.y) << 16);
  r.w = (unsigned)f2bf(b.z) | ((unsigned)f2bf(b.w) << 16);
  *(uint4*)(out + i) = r;
}

// ------- Wqkv [1024][3072] -> permuted transposed bf16 --------
__global__ void mha_perm_wqkv(const float* __restrict__ W,
                              unsigned short* __restrict__ wqkT,
                              unsigned short* __restrict__ wvT) {
  __shared__ float tile[32][33];
  int c0 = blockIdx.x * 32, k0 = blockIdx.y * 32;
  int tx = threadIdx.x, ty = threadIdx.y;
  for (int i = ty; i < 32; i += 8)
    tile[i][tx] = W[(size_t)(k0 + i) * 3072 + c0 + tx];
  __syncthreads();
  for (int i = ty; i < 32; i += 8) {
    int c = c0 + i;
    int hd = c / 3;
    int s = c - hd * 3;
    unsigned short v = f2bf(tile[tx][i]);
    if (s < 2) wqkT[(size_t)(s * 1024 + hd) * 1024 + k0 + tx] = v;
    else       wvT [(size_t)hd * 1024 + k0 + tx] = v;
  }
}

// ------- Wproj [1024][1024] -> transposed bf16 [c][k] --------
__global__ void mha_t_wproj(const float* __restrict__ W, unsigned short* __restrict__ wpT) {
  __shared__ float tile[32][33];
  int c0 = blockIdx.x * 32, k0 = blockIdx.y * 32;
  int tx = threadIdx.x, ty = threadIdx.y;
  for (int i = ty; i < 32; i += 8)
    tile[i][tx] = W[(size_t)(k0 + i) * 1024 + c0 + tx];
  __syncthreads();
  for (int i = ty; i < 32; i += 8)
    wpT[(size_t)(c0 + i) * 1024 + k0 + tx] = f2bf(tile[tx][i]);
}

// ---------------- 128x128 bf16 gemm_bt (m97-style) ----------------
template<int MODE>
__global__ __launch_bounds__(256, 2) void mha_gemm_bt(
    const unsigned short* __restrict__ A,
    const unsigned short* __restrict__ Bt,
    const float* __restrict__ bias,
    unsigned short* __restrict__ out_a,
    unsigned short* __restrict__ out_b,
    float* __restrict__ out_f)
{
  __shared__ __align__(16) unsigned short As[128 * 32];
  __shared__ __align__(16) unsigned short Bs[128 * 32];
  const int K = 1024;
  int t = threadIdx.x;
  int wv = t >> 6, lane = t & 63;
  int l15 = lane & 15, l4 = lane >> 4;
  int wr = wv >> 1, wc = wv & 1;
  int blkM = blockIdx.y * 128, blkN = blockIdx.x * 128;
  if (MODE == 1) Bt += (size_t)blockIdx.z * SEQ * D_MODEL;

  f32x4 acc[4][4];
  for (int m = 0; m < 4; m++) for (int n = 0; n < 4; n++) acc[m][n] = (f32x4){0.f,0.f,0.f,0.f};

  int srow = t >> 2;
  int skc  = (t & 3) * 8;
  for (int kt = 0; kt < K; kt += 32) {
    #pragma unroll
    for (int i = 0; i < 2; i++) {
      int e = i * 256 + t;
      int row = srow + i * 64;
      gload_lds16(A  + (size_t)(blkM + row) * K + kt + skc, As + e * 8);
      gload_lds16(Bt + (size_t)(blkN + row) * K + kt + skc, Bs + e * 8);
    }
    __syncthreads();
    short8 af[4], bf[4];
    #pragma unroll
    for (int m = 0; m < 4; m++)
      af[m] = *(const short8*)&As[(wr * 64 + m * 16 + l15) * 32 + l4 * 8];
    #pragma unroll
    for (int n = 0; n < 4; n++)
      bf[n] = *(const short8*)&Bs[(wc * 64 + n * 16 + l15) * 32 + l4 * 8];
    #pragma unroll
    for (int m = 0; m < 4; m++)
      #pragma unroll
      for (int n = 0; n < 4; n++)
        acc[m][n] = __builtin_amdgcn_mfma_f32_16x16x32_bf16(af[m], bf[n], acc[m][n], 0, 0, 0);
    __syncthreads();
  }

  int row0 = blkM + wr * 64;
  int col0 = blkN + wc * 64;
  #pragma unroll
  for (int m = 0; m < 4; m++) {
    #pragma unroll
    for (int n = 0; n < 4; n++) {
      int colb = col0 + n * 16 + l15;
      #pragma unroll
      for (int j = 0; j < 4; j++) {
        int row = row0 + m * 16 + l4 * 4 + j;
        float v = acc[m][n][j];
        if (MODE == 0) {
          int s = colb >> 10, hd = colb & 1023;
          v += bias[hd * 3 + s];
          if (s == 0) v *= 0.18033688011112042f;  // (1/8) * log2(e): fold softmax scale + exp2 base
          size_t idx = ((size_t)((row >> 11) * NHEADS + (hd >> 6)) * SEQ + (row & 2047)) * DEPTH + (hd & 63);
          (s == 0 ? out_a : out_b)[idx] = f2bf(v);
        } else if (MODE == 1) {
          v += bias[row * 3 + 2];
          out_a[((size_t)(blockIdx.z * 1024 + row)) * SEQ + colb] = f2bf(v);
        } else {
          v += bias[colb];
          out_f[(size_t)row * D_MODEL + colb] = v;
        }
      }
    }
  }
}

// -------- flash attention: 64 q-rows/wave (2 q-groups), halved LDS reads per MFMA --------
// Q [32][2048][64] bf16 (pre-scaled 0.125*log2e), K [32][2048][64] bf16, Vt [32][64][2048] bf16
// O  [B][2048][1024] bf16.
//
// Register blocking: each wave owns TWO 32-q-row groups; every K fragment read feeds
// 2 QK MFMAs, every V fragment read feeds 2 PV MFMAs -> LDS bytes per MFMA halved.
// 8 waves (512 thr), 256 blocks = 1 block/CU, 2 waves/SIMD.
// Wave w: qp=w>>1 (which 64 q-rows), kh=w&1 (which 32 keys of the staged 64).
// P = exp2f (OCML -> native v_exp_f32, compiler-visible so MFMA->VALU hazards are
// tracked; r8's inline-asm v_exp_f32 read MFMA accs without the mandated wait
// states -> 3.9e-2 error. NEVER read MFMA dst from inline asm).
// Staging: triple-buffered prefetch-2, counted vmcnt(2)+s_barrier (2 loads/thr/stage).
// Fixed-offset softmax (S acc init -12, offset cancels in (PV)/(P*1)); key-split
// partials combine linearly through LDS at the end.
__global__ __launch_bounds__(512, 2) void mha_attn(
    const unsigned short* __restrict__ Q,
    const unsigned short* __restrict__ Kb,
    const unsigned short* __restrict__ Vt,
    unsigned short* __restrict__ O)
{
  const int N = SEQ;
  const int NIT = N / 64;                    // 32
  int id = blockIdx.x;                       // 256 blocks
  int bh    = (id & 7) * 4 + ((id >> 6) & 3);  // 4 heads per XCD
  int qtile = (id >> 3) & 7;                 // 8 q-tiles of 256 rows
  int t = threadIdx.x, wv = t >> 6, lane = t & 63;
  int l31 = lane & 31, hi = lane >> 5;
  int kh = wv & 1, qp = wv >> 1;             // key-half, q-pair index 0..3

  __shared__ __align__(16) unsigned short SMEM[3 * 8192];  // 48KB: per buf {K[4096] | V[4096]}
  __shared__ float CMB[4][2][64][33];                      // 67.6KB combine scratch

  const unsigned short* Kbh = Kb + (size_t)bh * N * DEPTH;
  const unsigned short* Vbh = Vt + (size_t)bh * DEPTH * N;

  // Q fragments for two 32-row groups: rows qbase+l31 (A) and qbase+32+l31 (B)
  int qbase = qtile * 256 + qp * 64;
  const unsigned short* Qpt = Q + ((size_t)bh * N + qbase + l31) * DEPTH + hi * 8;
  short8 qfA[4], qfB[4];
  #pragma unroll
  for (int c = 0; c < 4; c++) {
    qfA[c] = *(const short8*)(Qpt + c * 16);
    qfB[c] = *(const short8*)(Qpt + 32 * DEPTH + c * 16);
  }

  // staging: thread t stages K granule t and V granule t (row t>>3, slot t&7)
  int srow = t >> 3;                         // 0..63
  int sc8  = ((t & 7) ^ (srow & 7)) * 8;     // pre-swizzled source column

  // swizzled LDS reads: tile row r, granule g -> elem r*64 + (g^(r&7))*8
  int rbK = (kh * 32 + l31) * 64;            // K rows: this wave's 32 keys
  int rbV0 = l31 * 64, rbV1 = rbV0 + 2048;   // V rows: d = l31 / l31+32
  int goQK[4], goPV[2];
  #pragma unroll
  for (int c = 0; c < 4; c++) goQK[c] = ((c * 2 + hi) ^ (l31 & 7)) * 8;
  #pragma unroll
  for (int lc = 0; lc < 2; lc++) goPV[lc] = ((kh * 4 + lc * 2 + hi) ^ (l31 & 7)) * 8;

  f32x16 o0a, o1a, o0b, o1b;
  #pragma unroll
  for (int i = 0; i < 16; i++) { o0a[i] = 0.f; o1a[i] = 0.f; o0b[i] = 0.f; o1b[i] = 0.f; }
  float lsA0 = 0.f, lsA1 = 0.f, lsA2 = 0.f, lsA3 = 0.f;
  float lsB0 = 0.f, lsB1 = 0.f, lsB2 = 0.f, lsB3 = 0.f;

#define STAGE(buf, kt)                                                                  \
  do {                                                                                  \
    unsigned short* base = SMEM + (buf) * 8192;                                         \
    gload_lds16(Kbh + (size_t)((kt) + srow) * DEPTH + sc8, base + t * 8);               \
    gload_lds16(Vbh + (size_t)srow * N + (kt) + sc8,       base + 4096 + t * 8);        \
  } while (0)

  // prologue: stage tiles 0,1; wait stage0 (2 loads of stage1 may stay outstanding)
  STAGE(0, 0);
  STAGE(1, 64);
  asm volatile("s_waitcnt vmcnt(2)" ::: "memory");
  __builtin_amdgcn_sched_barrier(0);
  __builtin_amdgcn_s_barrier();
  __builtin_amdgcn_sched_barrier(0);

  int cur = 0, sb = 2;                       // compute buf, stage-target buf
  for (int it = 0; it < NIT; ++it) {
    if (it + 2 < NIT) STAGE(sb, (it + 2) * 64);
    const unsigned short* Kc = SMEM + cur * 8192;
    const unsigned short* Vc = Kc + 4096;

    // ---- S^T = mfma(K_half, Q) for both q-groups; K frags read ONCE ----
    f32x16 sa, sb_;
    #pragma unroll
    for (int i = 0; i < 16; i++) { sa[i] = -12.0f; sb_[i] = -12.0f; }
    __builtin_amdgcn_s_setprio(1);
    #pragma unroll
    for (int c = 0; c < 4; c++) {
      short8 ka = *(const short8*)&Kc[rbK + goQK[c]];
      sa  = __builtin_amdgcn_mfma_f32_32x32x16_bf16(ka, qfA[c], sa,  0, 0, 0);
      sb_ = __builtin_amdgcn_mfma_f32_32x32x16_bf16(ka, qfB[c], sb_, 0, 0, 0);
    }
    __builtin_amdgcn_s_setprio(0);

    // ---- P = exp2(S') (compiler-visible native exp2), 4-way partial row-sums ----
    float pa[16], pb[16];
    #pragma unroll
    for (int r = 0; r < 16; r += 4) {
      pa[r]   = exp2f(sa[r]);   lsA0 += pa[r];
      pa[r+1] = exp2f(sa[r+1]); lsA1 += pa[r+1];
      pa[r+2] = exp2f(sa[r+2]); lsA2 += pa[r+2];
      pa[r+3] = exp2f(sa[r+3]); lsA3 += pa[r+3];
      pb[r]   = exp2f(sb_[r]);   lsB0 += pb[r];
      pb[r+1] = exp2f(sb_[r+1]); lsB1 += pb[r+1];
      pb[r+2] = exp2f(sb_[r+2]); lsB2 += pb[r+2];
      pb[r+3] = exp2f(sb_[r+3]); lsB3 += pb[r+3];
    }
    // ---- pack both groups, PV with V frags read ONCE ----
    #pragma unroll
    for (int lc = 0; lc < 2; lc++) {
      unsigned int A0 = cvt_pk_bf16(pa[8*lc+0], pa[8*lc+1]);
      unsigned int A1 = cvt_pk_bf16(pa[8*lc+2], pa[8*lc+3]);
      unsigned int A2 = cvt_pk_bf16(pa[8*lc+4], pa[8*lc+5]);
      unsigned int A3 = cvt_pk_bf16(pa[8*lc+6], pa[8*lc+7]);
      unsigned int B0 = cvt_pk_bf16(pb[8*lc+0], pb[8*lc+1]);
      unsigned int B1 = cvt_pk_bf16(pb[8*lc+2], pb[8*lc+3]);
      unsigned int B2 = cvt_pk_bf16(pb[8*lc+4], pb[8*lc+5]);
      unsigned int B3 = cvt_pk_bf16(pb[8*lc+6], pb[8*lc+7]);
      auto a02 = __builtin_amdgcn_permlane32_swap(A0, A2, false, false);
      auto a13 = __builtin_amdgcn_permlane32_swap(A1, A3, false, false);
      auto b02 = __builtin_amdgcn_permlane32_swap(B0, B2, false, false);
      auto b13 = __builtin_amdgcn_permlane32_swap(B1, B3, false, false);
      uint4v wa; wa[0] = a02[0]; wa[1] = a13[0]; wa[2] = a02[1]; wa[3] = a13[1];
      uint4v wb; wb[0] = b02[0]; wb[1] = b13[0]; wb[2] = b02[1]; wb[3] = b13[1];
      short8 bfA = __builtin_bit_cast(short8, wa);
      short8 bfB = __builtin_bit_cast(short8, wb);
      short8 va = *(const short8*)&Vc[rbV0 + goPV[lc]];
      short8 vb = *(const short8*)&Vc[rbV1 + goPV[lc]];
      __builtin_amdgcn_s_setprio(1);
      o0a = __builtin_amdgcn_mfma_f32_32x32x16_bf16(va, bfA, o0a, 0, 0, 0);
      o1a = __builtin_amdgcn_mfma_f32_32x32x16_bf16(vb, bfA, o1a, 0, 0, 0);
      o0b = __builtin_amdgcn_mfma_f32_32x32x16_bf16(va, bfB, o0b, 0, 0, 0);
      o1b = __builtin_amdgcn_mfma_f32_32x32x16_bf16(vb, bfB, o1b, 0, 0, 0);
      __builtin_amdgcn_s_setprio(0);
    }

    // ---- counted-vmcnt barrier: stage(it+1) done, stage(it+2) stays in flight ----
    if (it < NIT - 1) {
      if (it + 2 < NIT) asm volatile("s_waitcnt vmcnt(2)" ::: "memory");
      else              asm volatile("s_waitcnt vmcnt(0)" ::: "memory");
      __builtin_amdgcn_sched_barrier(0);
      __builtin_amdgcn_s_barrier();
      __builtin_amdgcn_sched_barrier(0);
    }
    cur = (cur == 2) ? 0 : cur + 1;
    sb  = (sb  == 2) ? 0 : sb  + 1;
  }
#undef STAGE

  float lsA = (lsA0 + lsA1) + (lsA2 + lsA3);
  float lsB = (lsB0 + lsB1) + (lsB2 + lsB3);
  lsA += __shfl_xor(lsA, 32);
  lsB += __shfl_xor(lsB, 32);

  // ---- combine key-split partials across wave pairs (same qp, kh 0/1) ----
  if (kh == 1) {
    float* cA = &CMB[qp][0][lane][0];
    float* cB = &CMB[qp][1][lane][0];
    #pragma unroll
    for (int i = 0; i < 16; i++) {
      cA[i] = o0a[i]; cA[16 + i] = o1a[i];
      cB[i] = o0b[i]; cB[16 + i] = o1b[i];
    }
    cA[32] = lsA; cB[32] = lsB;
  }
  __syncthreads();
  if (kh == 0) {
    const float* cA = &CMB[qp][0][lane][0];
    const float* cB = &CMB[qp][1][lane][0];
    #pragma unroll
    for (int i = 0; i < 16; i++) {
      o0a[i] += cA[i]; o1a[i] += cA[16 + i];
      o0b[i] += cB[i]; o1b[i] += cB[16 + i];
    }
    float rlA = 1.0f / (lsA + cA[32]);
    float rlB = 1.0f / (lsB + cB[32]);

    int b = bh >> 4, h = bh & 15;
    unsigned short* OpA = O + ((size_t)b * N + qbase + l31) * D_MODEL + h * DEPTH;
    unsigned short* OpB = OpA + (size_t)32 * D_MODEL;
    // acc layout: col q = l31, row d = (reg&3) + 8*(reg>>2) + 4*hi (+32 for o1)
    #pragma unroll
    for (int gq = 0; gq < 4; gq++) {
      #pragma unroll
      for (int rp = 0; rp < 2; rp++) {
        int reg = gq * 4 + rp * 2;
        int d = gq * 8 + hi * 4 + rp * 2;
        *(unsigned int*)(OpA + d)      = cvt_pk_bf16(o0a[reg] * rlA, o0a[reg + 1] * rlA);
        *(unsigned int*)(OpA + 32 + d) = cvt_pk_bf16(o1a[reg] * rlA, o1a[reg + 1] * rlA);
        *(unsigned int*)(OpB + d)      = cvt_pk_bf16(o0b[reg] * rlB, o0b[reg + 1] * rlB);
        *(unsigned int*)(OpB + 32 + d) = cvt_pk_bf16(o1b[reg] * rlB, o1b[reg + 1] * rlB);
      }
    }
  }
}

extern "C" void kernel_launch(void* const* d_in, const int* in_sizes, int n_in,
                              void* d_out, int out_size, void* d_ws, size_t ws_size,
                              hipStream_t stream) {
  const float* x     = (const float*)d_in[0];
  const float* Wqkv  = (const float*)d_in[1];
  const float* bqkv  = (const float*)d_in[2];
  const float* Wproj = (const float*)d_in[3];
  const float* bproj = (const float*)d_in[4];
  float* out = (float*)d_out;

  char* w = (char*)d_ws;
  unsigned short* xb    = (unsigned short*)(w);                       // 8 MB
  unsigned short* wqkT  = (unsigned short*)(w + 8388608);             // 4 MB
  unsigned short* wvT   = (unsigned short*)(w + 8388608 + 4194304);   // 2 MB
  unsigned short* wpT   = (unsigned short*)(w + 8388608 + 4194304 + 2097152);  // 2 MB
  unsigned short* Qbuf  = (unsigned short*)(w + 16777216);            // 8 MB
  unsigned short* Kbuf  = (unsigned short*)(w + 16777216 + 8388608);  // 8 MB
  unsigned short* Vtb   = (unsigned short*)(w + 16777216 + 16777216); // 8 MB
  unsigned short* AOut  = (unsigned short*)(w + 16777216 + 25165824); // 8 MB

  // 1. x -> bf16
  mha_cvt_bf16<<<M_TOK * D_MODEL / (256 * 8), 256, 0, stream>>>(x, xb);
  // 2. Wqkv -> permuted transposed bf16 (QK part + V part)
  mha_perm_wqkv<<<dim3(96, 32), dim3(32, 8), 0, stream>>>(Wqkv, wqkT, wvT);
  // 3. Wproj -> transposed bf16
  mha_t_wproj<<<dim3(32, 32), dim3(32, 8), 0, stream>>>(Wproj, wpT);
  // 4. QK gemm: [4096 x 2048]
  mha_gemm_bt<0><<<dim3(16, 32), 256, 0, stream>>>(xb, wqkT, bqkv, Qbuf, Kbuf, nullptr);
  // 5. V gemm (transposed output): per batch [1024 x 2048]
  mha_gemm_bt<1><<<dim3(16, 8, 2), 256, 0, stream>>>(wvT, xb, bqkv, Vtb, nullptr, nullptr);
  // 6. flash attention (256 blocks, 512 threads: 1 block/CU, 2 waves/SIMD)
  mha_attn<<<256, 512, 0, stream>>>(Qbuf, Kbuf, Vtb, AOut);
  // 7. projection gemm -> fp32 out
  mha_gemm_bt<2><<<dim3(8, 32), 256, 0, stream>>>(AOut, wpT, bproj, nullptr, nullptr, out);
}

// Round 10
// 132.342 us; speedup vs baseline: 1.1648x; 1.1648x over previous
//
#include <hip/hip_runtime.h>
#include <stdint.h>

#define D_MODEL 1024
#define NHEADS  16
#define DEPTH   64
#define BATCH   2
#define SEQ     2048
#define M_TOK   (BATCH*SEQ)   // 4096

typedef __attribute__((ext_vector_type(8)))  short short8;
typedef __attribute__((ext_vector_type(4)))  float f32x4;
typedef __attribute__((ext_vector_type(16))) float f32x16;
typedef __attribute__((ext_vector_type(4)))  unsigned int uint4v;

__device__ __forceinline__ unsigned short f2bf(float f) {
  unsigned int u = __float_as_uint(f);
  u += 0x7fffu + ((u >> 16) & 1u);
  return (unsigned short)(u >> 16);
}

__device__ __forceinline__ unsigned int cvt_pk_bf16(float lo, float hi) {
  unsigned int r;
  asm("v_cvt_pk_bf16_f32 %0, %1, %2" : "=v"(r) : "v"(lo), "v"(hi));
  return r;
}

__device__ __forceinline__ void gload_lds16(const unsigned short* g, unsigned short* l) {
  __builtin_amdgcn_global_load_lds((const __attribute__((address_space(1))) void*)g,
                                   (__attribute__((address_space(3))) void*)l, 16, 0, 0);
}

// ------------- merged prep: x->bf16 | Wqkv permute-transpose | Wproj transpose -------------
// grid 6144 x 256thr: [0,2048) cvt, [2048,5120) perm (96x32), [5120,6144) wproj (32x32)
__global__ void mha_prep(const float* __restrict__ x, const float* __restrict__ Wqkv,
                         const float* __restrict__ Wproj,
                         unsigned short* __restrict__ xb,
                         unsigned short* __restrict__ wqkT,
                         unsigned short* __restrict__ wvT,
                         unsigned short* __restrict__ wpT) {
  __shared__ float tile[32][33];
  int id = blockIdx.x, t = threadIdx.x;
  if (id < 2048) {
    int i = (id * 256 + t) * 8;
    float4 a = *(const float4*)(x + i);
    float4 b = *(const float4*)(x + i + 4);
    uint4 r;
    r.x = (unsigned)f2bf(a.x) | ((unsigned)f2bf(a.y) << 16);
    r.y = (unsigned)f2bf(a.z) | ((unsigned)f2bf(a.w) << 16);
    r.z = (unsigned)f2bf(b.x) | ((unsigned)f2bf(b.y) << 16);
    r.w = (unsigned)f2bf(b.z) | ((unsigned)f2bf(b.w) << 16);
    *(uint4*)(xb + i) = r;
  } else if (id < 5120) {
    int b = id - 2048;
    int c0 = (b % 96) * 32, k0 = (b / 96) * 32;
    int tx = t & 31, ty = t >> 5;
    for (int i = ty; i < 32; i += 8)
      tile[i][tx] = Wqkv[(size_t)(k0 + i) * 3072 + c0 + tx];
    __syncthreads();
    for (int i = ty; i < 32; i += 8) {
      int c = c0 + i;
      int hd = c / 3;
      int s = c - hd * 3;
      unsigned short v = f2bf(tile[tx][i]);
      if (s < 2) wqkT[(size_t)(s * 1024 + hd) * 1024 + k0 + tx] = v;
      else       wvT [(size_t)hd * 1024 + k0 + tx] = v;
    }
  } else {
    int b = id - 5120;
    int c0 = (b & 31) * 32, k0 = (b >> 5) * 32;
    int tx = t & 31, ty = t >> 5;
    for (int i = ty; i < 32; i += 8)
      tile[i][tx] = Wproj[(size_t)(k0 + i) * 1024 + c0 + tx];
    __syncthreads();
    for (int i = ty; i < 32; i += 8)
      wpT[(size_t)(c0 + i) * 1024 + k0 + tx] = f2bf(tile[tx][i]);
  }
}

// ------------- merged QKV gemm: blocks [0,512) = QK part, [512,768) = V part -------------
// 128x128 bf16 gemm_bt core (m97-style). One dispatch: better tail overlap, one less launch.
__global__ __launch_bounds__(256, 2) void mha_gemm_qkv(
    const unsigned short* __restrict__ xb,
    const unsigned short* __restrict__ wqkT,
    const unsigned short* __restrict__ wvT,
    const float* __restrict__ bias,
    unsigned short* __restrict__ Qb,
    unsigned short* __restrict__ Kb,
    unsigned short* __restrict__ Vtb)
{
  __shared__ __align__(16) unsigned short As[128 * 32];
  __shared__ __align__(16) unsigned short Bs[128 * 32];
  const int K = 1024;
  int id = blockIdx.x;
  bool m0 = id < 512;
  int bx, by, bz = 0;
  const unsigned short *A, *Bt;
  if (m0) { bx = id & 15; by = id >> 4; A = xb; Bt = wqkT; }
  else {
    int b2 = id - 512;
    bx = b2 & 15; by = (b2 >> 4) & 7; bz = b2 >> 7;
    A = wvT; Bt = xb + (size_t)bz * SEQ * D_MODEL;
  }
  int t = threadIdx.x;
  int wv = t >> 6, lane = t & 63;
  int l15 = lane & 15, l4 = lane >> 4;
  int wr = wv >> 1, wc = wv & 1;
  int blkM = by * 128, blkN = bx * 128;

  f32x4 acc[4][4];
  for (int m = 0; m < 4; m++) for (int n = 0; n < 4; n++) acc[m][n] = (f32x4){0.f,0.f,0.f,0.f};

  int srow = t >> 2;
  int skc  = (t & 3) * 8;
  for (int kt = 0; kt < K; kt += 32) {
    #pragma unroll
    for (int i = 0; i < 2; i++) {
      int e = i * 256 + t;
      int row = srow + i * 64;
      gload_lds16(A  + (size_t)(blkM + row) * K + kt + skc, As + e * 8);
      gload_lds16(Bt + (size_t)(blkN + row) * K + kt + skc, Bs + e * 8);
    }
    __syncthreads();
    short8 af[4], bf[4];
    #pragma unroll
    for (int m = 0; m < 4; m++)
      af[m] = *(const short8*)&As[(wr * 64 + m * 16 + l15) * 32 + l4 * 8];
    #pragma unroll
    for (int n = 0; n < 4; n++)
      bf[n] = *(const short8*)&Bs[(wc * 64 + n * 16 + l15) * 32 + l4 * 8];
    #pragma unroll
    for (int m = 0; m < 4; m++)
      #pragma unroll
      for (int n = 0; n < 4; n++)
        acc[m][n] = __builtin_amdgcn_mfma_f32_16x16x32_bf16(af[m], bf[n], acc[m][n], 0, 0, 0);
    __syncthreads();
  }

  int row0 = blkM + wr * 64;
  int col0 = blkN + wc * 64;
  #pragma unroll
  for (int m = 0; m < 4; m++) {
    #pragma unroll
    for (int n = 0; n < 4; n++) {
      int colb = col0 + n * 16 + l15;
      #pragma unroll
      for (int j = 0; j < 4; j++) {
        int row = row0 + m * 16 + l4 * 4 + j;
        float v = acc[m][n][j];
        if (m0) {
          int s = colb >> 10, hd = colb & 1023;
          v += bias[hd * 3 + s];
          if (s == 0) v *= 0.18033688011112042f;  // (1/8)*log2(e): softmax scale + exp2 base
          size_t idx = ((size_t)((row >> 11) * NHEADS + (hd >> 6)) * SEQ + (row & 2047)) * DEPTH + (hd & 63);
          (s == 0 ? Qb : Kb)[idx] = f2bf(v);
        } else {
          v += bias[row * 3 + 2];
          Vtb[((size_t)(bz * 1024 + row)) * SEQ + colb] = f2bf(v);
        }
      }
    }
  }
}

// ---------------- proj gemm (fp32 out) ----------------
__global__ __launch_bounds__(256, 2) void mha_gemm_proj(
    const unsigned short* __restrict__ A,
    const unsigned short* __restrict__ Bt,
    const float* __restrict__ bias,
    float* __restrict__ out_f)
{
  __shared__ __align__(16) unsigned short As[128 * 32];
  __shared__ __align__(16) unsigned short Bs[128 * 32];
  const int K = 1024;
  int t = threadIdx.x;
  int wv = t >> 6, lane = t & 63;
  int l15 = lane & 15, l4 = lane >> 4;
  int wr = wv >> 1, wc = wv & 1;
  int blkM = blockIdx.y * 128, blkN = blockIdx.x * 128;

  f32x4 acc[4][4];
  for (int m = 0; m < 4; m++) for (int n = 0; n < 4; n++) acc[m][n] = (f32x4){0.f,0.f,0.f,0.f};

  int srow = t >> 2;
  int skc  = (t & 3) * 8;
  for (int kt = 0; kt < K; kt += 32) {
    #pragma unroll
    for (int i = 0; i < 2; i++) {
      int e = i * 256 + t;
      int row = srow + i * 64;
      gload_lds16(A  + (size_t)(blkM + row) * K + kt + skc, As + e * 8);
      gload_lds16(Bt + (size_t)(blkN + row) * K + kt + skc, Bs + e * 8);
    }
    __syncthreads();
    short8 af[4], bf[4];
    #pragma unroll
    for (int m = 0; m < 4; m++)
      af[m] = *(const short8*)&As[(wr * 64 + m * 16 + l15) * 32 + l4 * 8];
    #pragma unroll
    for (int n = 0; n < 4; n++)
      bf[n] = *(const short8*)&Bs[(wc * 64 + n * 16 + l15) * 32 + l4 * 8];
    #pragma unroll
    for (int m = 0; m < 4; m++)
      #pragma unroll
      for (int n = 0; n < 4; n++)
        acc[m][n] = __builtin_amdgcn_mfma_f32_16x16x32_bf16(af[m], bf[n], acc[m][n], 0, 0, 0);
    __syncthreads();
  }

  int row0 = blkM + wr * 64;
  int col0 = blkN + wc * 64;
  #pragma unroll
  for (int m = 0; m < 4; m++) {
    #pragma unroll
    for (int n = 0; n < 4; n++) {
      int colb = col0 + n * 16 + l15;
      #pragma unroll
      for (int j = 0; j < 4; j++) {
        int row = row0 + m * 16 + l4 * 4 + j;
        out_f[(size_t)row * D_MODEL + colb] = acc[m][n][j] + bias[colb];
      }
    }
  }
}

// -------- flash attention: VALU diet (static addrs, ones-MFMA lsum, no offset) --------
// Q [32][2048][64] bf16 (pre-scaled 0.125*log2e), K [32][2048][64] bf16, Vt [32][64][2048] bf16
// O [B][2048][1024] bf16.
// 512 blocks x 512 thr = 2 blocks/CU, 16 waves/CU (the r4-r9 invariant: waves/CU is the
// only knob that moved perf). Wave w: qh=w>>1 (32 of 128 q-rows), kh=w&1 (32-key half).
// Diet vs r7: (1) 2-buffer unroll-2 loop -> static LDS bases, near-zero addr VALU;
// (2) row-sum lsacc = mfma(ones, bfrag, lsacc) replaces 16 v_adds/iter AND the end shfl
// (MFMA sums all k of the slice internally; every acc reg = colsum);
// (3) softmax offset dropped entirely (P=exp2(S'), |S'|<~10, cancels in (PV)/(P*1)).
// K/V: XOR-swizzle via pre-swizzled global source (both-sides involution, rule #21).
__global__ __launch_bounds__(512, 2) void mha_attn(
    const unsigned short* __restrict__ Q,
    const unsigned short* __restrict__ Kb,
    const unsigned short* __restrict__ Vt,
    unsigned short* __restrict__ O)
{
  const int N = SEQ;
  const int NIT = N / 64;                    // 32
  int id = blockIdx.x;                       // 512 blocks
  int bh    = (id & 7) * 4 + ((id >> 7) & 3);  // 4 heads per XCD
  int qtile = (id >> 3) & 15;                // 16 q-tiles of 128 rows
  int t = threadIdx.x, wv = t >> 6, lane = t & 63;
  int l31 = lane & 31, hi = lane >> 5;
  int kh = wv & 1, qh = wv >> 1;             // key-half, q-group 0..3

  __shared__ __align__(16) unsigned short SMEM[2 * 8192];  // 32KB: per buf {K[4096]|V[4096]}
  __shared__ float CMB[4][64][33];                         // 33.8KB combine scratch

  const unsigned short* Kbh = Kb + (size_t)bh * N * DEPTH;
  const unsigned short* Vbh = Vt + (size_t)bh * DEPTH * N;

  int qrow = qtile * 128 + qh * 32 + l31;
  const unsigned short* Qp = Q + ((size_t)bh * N + qrow) * DEPTH + hi * 8;
  short8 qf[4];
  #pragma unroll
  for (int c = 0; c < 4; c++) qf[c] = *(const short8*)(Qp + c * 16);

  // staging: thread t stages K granule t and V granule t (row t>>3, slot t&7)
  int srow = t >> 3;                         // 0..63
  int sc8  = ((t & 7) ^ (srow & 7)) * 8;     // pre-swizzled source column
  const unsigned short* kst = Kbh + (size_t)srow * DEPTH + sc8;
  const unsigned short* vst = Vbh + (size_t)srow * N + sc8;

  // swizzled LDS reads: tile row r, granule g -> elem r*64 + (g^(r&7))*8
  int rbK = (kh * 32 + l31) * 64;
  int rbV0 = l31 * 64, rbV1 = rbV0 + 2048;
  int goQK[4], goPV[2];
  #pragma unroll
  for (int c = 0; c < 4; c++) goQK[c] = ((c * 2 + hi) ^ (l31 & 7)) * 8;
  #pragma unroll
  for (int lc = 0; lc < 2; lc++) goPV[lc] = ((kh * 4 + lc * 2 + hi) ^ (l31 & 7)) * 8;

  short8 ones;
  #pragma unroll
  for (int i = 0; i < 8; i++) ones[i] = (short)0x3F80;   // bf16 1.0

  f32x16 o0, o1, lsacc;
  #pragma unroll
  for (int i = 0; i < 16; i++) { o0[i] = 0.f; o1[i] = 0.f; lsacc[i] = 0.f; }

  // prologue: stage tile 0 into buf 0
  gload_lds16(kst, SMEM + t * 8);
  gload_lds16(vst, SMEM + 4096 + t * 8);
  asm volatile("s_waitcnt vmcnt(0)" ::: "memory");
  __builtin_amdgcn_sched_barrier(0);
  __builtin_amdgcn_s_barrier();
  __builtin_amdgcn_sched_barrier(0);

#define BODY(BUF, IT)                                                                   \
  do {                                                                                  \
    if ((IT) + 1 < NIT) {                                                               \
      gload_lds16(kst + (size_t)((IT) + 1) * 4096, SMEM + ((BUF) ^ 1) * 8192 + t * 8);  \
      gload_lds16(vst + ((IT) + 1) * 64, SMEM + ((BUF) ^ 1) * 8192 + 4096 + t * 8);     \
    }                                                                                   \
    {                                                                                   \
      const unsigned short* Kc = SMEM + (BUF) * 8192;                                   \
      const unsigned short* Vc = Kc + 4096;                                             \
      f32x16 s;                                                                         \
      _Pragma("unroll") for (int i = 0; i < 16; i++) s[i] = 0.f;                        \
      __builtin_amdgcn_s_setprio(1);                                                    \
      _Pragma("unroll") for (int c = 0; c < 4; c++) {                                   \
        short8 ka = *(const short8*)&Kc[rbK + goQK[c]];                                 \
        s = __builtin_amdgcn_mfma_f32_32x32x16_bf16(ka, qf[c], s, 0, 0, 0);             \
      }                                                                                 \
      __builtin_amdgcn_s_setprio(0);                                                    \
      float p[16];                                                                      \
      _Pragma("unroll") for (int r = 0; r < 16; r++) p[r] = exp2f(s[r]);                \
      _Pragma("unroll") for (int lc = 0; lc < 2; lc++) {                                \
        unsigned int X0 = cvt_pk_bf16(p[8*lc+0], p[8*lc+1]);                            \
        unsigned int X1 = cvt_pk_bf16(p[8*lc+2], p[8*lc+3]);                            \
        unsigned int X2 = cvt_pk_bf16(p[8*lc+4], p[8*lc+5]);                            \
        unsigned int X3 = cvt_pk_bf16(p[8*lc+6], p[8*lc+7]);                            \
        auto r02 = __builtin_amdgcn_permlane32_swap(X0, X2, false, false);              \
        auto r13 = __builtin_amdgcn_permlane32_swap(X1, X3, false, false);              \
        uint4v wvec; wvec[0] = r02[0]; wvec[1] = r13[0]; wvec[2] = r02[1]; wvec[3] = r13[1]; \
        short8 bfrag = __builtin_bit_cast(short8, wvec);                                \
        short8 va = *(const short8*)&Vc[rbV0 + goPV[lc]];                               \
        short8 vb = *(const short8*)&Vc[rbV1 + goPV[lc]];                               \
        __builtin_amdgcn_s_setprio(1);                                                  \
        o0 = __builtin_amdgcn_mfma_f32_32x32x16_bf16(va, bfrag, o0, 0, 0, 0);           \
        o1 = __builtin_amdgcn_mfma_f32_32x32x16_bf16(vb, bfrag, o1, 0, 0, 0);           \
        lsacc = __builtin_amdgcn_mfma_f32_32x32x16_bf16(ones, bfrag, lsacc, 0, 0, 0);   \
        __builtin_amdgcn_s_setprio(0);                                                  \
      }                                                                                 \
    }                                                                                   \
    if ((IT) + 1 < NIT) {                                                               \
      asm volatile("s_waitcnt vmcnt(0)" ::: "memory");                                  \
      __builtin_amdgcn_sched_barrier(0);                                                \
      __builtin_amdgcn_s_barrier();                                                     \
      __builtin_amdgcn_sched_barrier(0);                                                \
    }                                                                                   \
  } while (0)

  for (int it2 = 0; it2 < NIT; it2 += 2) {
    BODY(0, it2);
    BODY(1, it2 + 1);
  }
#undef BODY

  float ls = lsacc[0];   // every acc reg = sum over all keys of this wave's half

  // ---- combine key-split partials across wave pairs (same qh, kh 0/1) ----
  if (kh == 1) {
    float* c0 = &CMB[qh][lane][0];
    #pragma unroll
    for (int i = 0; i < 16; i++) { c0[i] = o0[i]; c0[16 + i] = o1[i]; }
    c0[32] = ls;
  }
  __syncthreads();
  if (kh == 0) {
    const float* c0 = &CMB[qh][lane][0];
    #pragma unroll
    for (int i = 0; i < 16; i++) { o0[i] += c0[i]; o1[i] += c0[16 + i]; }
    float rl = 1.0f / (ls + c0[32]);

    int b = bh >> 4, h = bh & 15;
    unsigned short* Op = O + ((size_t)b * N + qrow) * D_MODEL + h * DEPTH;
    // acc layout: col q = l31, row d = (reg&3) + 8*(reg>>2) + 4*hi (+32 for o1)
    #pragma unroll
    for (int gq = 0; gq < 4; gq++) {
      #pragma unroll
      for (int rp = 0; rp < 2; rp++) {
        int reg = gq * 4 + rp * 2;
        int d = gq * 8 + hi * 4 + rp * 2;
        *(unsigned int*)(Op + d)      = cvt_pk_bf16(o0[reg] * rl, o0[reg + 1] * rl);
        *(unsigned int*)(Op + 32 + d) = cvt_pk_bf16(o1[reg] * rl, o1[reg + 1] * rl);
      }
    }
  }
}

extern "C" void kernel_launch(void* const* d_in, const int* in_sizes, int n_in,
                              void* d_out, int out_size, void* d_ws, size_t ws_size,
                              hipStream_t stream) {
  const float* x     = (const float*)d_in[0];
  const float* Wqkv  = (const float*)d_in[1];
  const float* bqkv  = (const float*)d_in[2];
  const float* Wproj = (const float*)d_in[3];
  const float* bproj = (const float*)d_in[4];
  float* out = (float*)d_out;

  char* w = (char*)d_ws;
  unsigned short* xb    = (unsigned short*)(w);                       // 8 MB
  unsigned short* wqkT  = (unsigned short*)(w + 8388608);             // 4 MB
  unsigned short* wvT   = (unsigned short*)(w + 8388608 + 4194304);   // 2 MB
  unsigned short* wpT   = (unsigned short*)(w + 8388608 + 4194304 + 2097152);  // 2 MB
  unsigned short* Qbuf  = (unsigned short*)(w + 16777216);            // 8 MB
  unsigned short* Kbuf  = (unsigned short*)(w + 16777216 + 8388608);  // 8 MB
  unsigned short* Vtb   = (unsigned short*)(w + 16777216 + 16777216); // 8 MB
  unsigned short* AOut  = (unsigned short*)(w + 16777216 + 25165824); // 8 MB

  // 1. merged prep (x cvt + Wqkv permute + Wproj transpose)
  mha_prep<<<6144, 256, 0, stream>>>(x, Wqkv, Wproj, xb, wqkT, wvT, wpT);
  // 2. merged QKV gemm (QK part: 512 blocks, V part: 256 blocks)
  mha_gemm_qkv<<<768, 256, 0, stream>>>(xb, wqkT, wvT, bqkv, Qbuf, Kbuf, Vtb);
  // 3. flash attention (512 blocks x 512 thr = 2 blocks/CU, 16 waves/CU)
  mha_attn<<<512, 512, 0, stream>>>(Qbuf, Kbuf, Vtb, AOut);
  // 4. projection gemm -> fp32 out
  mha_gemm_proj<<<dim3(8, 32), 256, 0, stream>>>(AOut, wpT, bproj, out);
}

// Round 11
// 119.787 us; speedup vs baseline: 1.2868x; 1.1048x over previous
//
#include <hip/hip_runtime.h>
#include <stdint.h>

#define D_MODEL 1024
#define NHEADS  16
#define DEPTH   64
#define BATCH   2
#define SEQ     2048
#define M_TOK   (BATCH*SEQ)   // 4096

typedef __attribute__((ext_vector_type(8)))  short short8;
typedef __attribute__((ext_vector_type(4)))  float f32x4;
typedef __attribute__((ext_vector_type(16))) float f32x16;
typedef __attribute__((ext_vector_type(4)))  unsigned int uint4v;

#if defined(__has_builtin)
#if __has_builtin(__builtin_amdgcn_exp2f)
#define EXP2(x) __builtin_amdgcn_exp2f(x)
#endif
#endif
#ifndef EXP2
#define EXP2(x) exp2f(x)
#endif

__device__ __forceinline__ unsigned short f2bf(float f) {
  unsigned int u = __float_as_uint(f);
  u += 0x7fffu + ((u >> 16) & 1u);
  return (unsigned short)(u >> 16);
}

__device__ __forceinline__ unsigned int cvt_pk_bf16(float lo, float hi) {
  unsigned int r;
  asm("v_cvt_pk_bf16_f32 %0, %1, %2" : "=v"(r) : "v"(lo), "v"(hi));
  return r;
}

__device__ __forceinline__ void gload_lds16(const unsigned short* g, unsigned short* l) {
  __builtin_amdgcn_global_load_lds((const __attribute__((address_space(1))) void*)g,
                                   (__attribute__((address_space(3))) void*)l, 16, 0, 0);
}

// ------------- merged prep: x->bf16 | Wqkv permute-transpose | Wproj transpose -------------
__global__ void mha_prep(const float* __restrict__ x, const float* __restrict__ Wqkv,
                         const float* __restrict__ Wproj,
                         unsigned short* __restrict__ xb,
                         unsigned short* __restrict__ wqkT,
                         unsigned short* __restrict__ wvT,
                         unsigned short* __restrict__ wpT) {
  __shared__ float tile[32][33];
  int id = blockIdx.x, t = threadIdx.x;
  if (id < 2048) {
    int i = (id * 256 + t) * 8;
    float4 a = *(const float4*)(x + i);
    float4 b = *(const float4*)(x + i + 4);
    uint4 r;
    r.x = (unsigned)f2bf(a.x) | ((unsigned)f2bf(a.y) << 16);
    r.y = (unsigned)f2bf(a.z) | ((unsigned)f2bf(a.w) << 16);
    r.z = (unsigned)f2bf(b.x) | ((unsigned)f2bf(b.y) << 16);
    r.w = (unsigned)f2bf(b.z) | ((unsigned)f2bf(b.w) << 16);
    *(uint4*)(xb + i) = r;
  } else if (id < 5120) {
    int b = id - 2048;
    int c0 = (b % 96) * 32, k0 = (b / 96) * 32;
    int tx = t & 31, ty = t >> 5;
    for (int i = ty; i < 32; i += 8)
      tile[i][tx] = Wqkv[(size_t)(k0 + i) * 3072 + c0 + tx];
    __syncthreads();
    for (int i = ty; i < 32; i += 8) {
      int c = c0 + i;
      int hd = c / 3;
      int s = c - hd * 3;
      unsigned short v = f2bf(tile[tx][i]);
      if (s < 2) wqkT[(size_t)(s * 1024 + hd) * 1024 + k0 + tx] = v;
      else       wvT [(size_t)hd * 1024 + k0 + tx] = v;
    }
  } else {
    int b = id - 5120;
    int c0 = (b & 31) * 32, k0 = (b >> 5) * 32;
    int tx = t & 31, ty = t >> 5;
    for (int i = ty; i < 32; i += 8)
      tile[i][tx] = Wproj[(size_t)(k0 + i) * 1024 + c0 + tx];
    __syncthreads();
    for (int i = ty; i < 32; i += 8)
      wpT[(size_t)(c0 + i) * 1024 + k0 + tx] = f2bf(tile[tx][i]);
  }
}

// ------------- merged QKV gemm: blocks [0,512) = QK part, [512,768) = V part -------------
// (256,3): force VGPR<=168 for 3 blocks/CU (m97-equivalent occupancy; m97 fit in 164).
__global__ __launch_bounds__(256, 3) void mha_gemm_qkv(
    const unsigned short* __restrict__ xb,
    const unsigned short* __restrict__ wqkT,
    const unsigned short* __restrict__ wvT,
    const float* __restrict__ bias,
    unsigned short* __restrict__ Qb,
    unsigned short* __restrict__ Kb,
    unsigned short* __restrict__ Vtb)
{
  __shared__ __align__(16) unsigned short As[128 * 32];
  __shared__ __align__(16) unsigned short Bs[128 * 32];
  const int K = 1024;
  int id = blockIdx.x;
  bool m0 = id < 512;
  int bx, by, bz = 0;
  const unsigned short *A, *Bt;
  if (m0) { bx = id & 15; by = id >> 4; A = xb; Bt = wqkT; }
  else {
    int b2 = id - 512;
    bx = b2 & 15; by = (b2 >> 4) & 7; bz = b2 >> 7;
    A = wvT; Bt = xb + (size_t)bz * SEQ * D_MODEL;
  }
  int t = threadIdx.x;
  int wv = t >> 6, lane = t & 63;
  int l15 = lane & 15, l4 = lane >> 4;
  int wr = wv >> 1, wc = wv & 1;
  int blkM = by * 128, blkN = bx * 128;

  f32x4 acc[4][4];
  for (int m = 0; m < 4; m++) for (int n = 0; n < 4; n++) acc[m][n] = (f32x4){0.f,0.f,0.f,0.f};

  int srow = t >> 2;
  int skc  = (t & 3) * 8;
  for (int kt = 0; kt < K; kt += 32) {
    #pragma unroll
    for (int i = 0; i < 2; i++) {
      int e = i * 256 + t;
      int row = srow + i * 64;
      gload_lds16(A  + (size_t)(blkM + row) * K + kt + skc, As + e * 8);
      gload_lds16(Bt + (size_t)(blkN + row) * K + kt + skc, Bs + e * 8);
    }
    __syncthreads();
    short8 af[4], bf[4];
    #pragma unroll
    for (int m = 0; m < 4; m++)
      af[m] = *(const short8*)&As[(wr * 64 + m * 16 + l15) * 32 + l4 * 8];
    #pragma unroll
    for (int n = 0; n < 4; n++)
      bf[n] = *(const short8*)&Bs[(wc * 64 + n * 16 + l15) * 32 + l4 * 8];
    #pragma unroll
    for (int m = 0; m < 4; m++)
      #pragma unroll
      for (int n = 0; n < 4; n++)
        acc[m][n] = __builtin_amdgcn_mfma_f32_16x16x32_bf16(af[m], bf[n], acc[m][n], 0, 0, 0);
    __syncthreads();
  }

  int row0 = blkM + wr * 64;
  int col0 = blkN + wc * 64;
  #pragma unroll
  for (int m = 0; m < 4; m++) {
    #pragma unroll
    for (int n = 0; n < 4; n++) {
      int colb = col0 + n * 16 + l15;
      #pragma unroll
      for (int j = 0; j < 4; j++) {
        int row = row0 + m * 16 + l4 * 4 + j;
        float v = acc[m][n][j];
        if (m0) {
          int s = colb >> 10, hd = colb & 1023;
          v += bias[hd * 3 + s];
          if (s == 0) v *= 0.18033688011112042f;  // (1/8)*log2(e): softmax scale + exp2 base
          size_t idx = ((size_t)((row >> 11) * NHEADS + (hd >> 6)) * SEQ + (row & 2047)) * DEPTH + (hd & 63);
          (s == 0 ? Qb : Kb)[idx] = f2bf(v);
        } else {
          v += bias[row * 3 + 2];
          Vtb[((size_t)(bz * 1024 + row)) * SEQ + colb] = f2bf(v);
        }
      }
    }
  }
}

// ---------------- proj gemm (fp32 out): 128x64 tiles, 512 blocks = 2/CU ----------------
__global__ __launch_bounds__(256, 3) void mha_gemm_proj(
    const unsigned short* __restrict__ A,
    const unsigned short* __restrict__ Bt,
    const float* __restrict__ bias,
    float* __restrict__ out_f)
{
  __shared__ __align__(16) unsigned short As[128 * 32];
  __shared__ __align__(16) unsigned short Bs[64 * 32];
  const int K = 1024;
  int t = threadIdx.x;
  int wv = t >> 6, lane = t & 63;
  int l15 = lane & 15, l4 = lane >> 4;
  int wr = wv >> 1, wc = wv & 1;
  int blkM = blockIdx.y * 128, blkN = blockIdx.x * 64;

  f32x4 acc[4][2];
  for (int m = 0; m < 4; m++) for (int n = 0; n < 2; n++) acc[m][n] = (f32x4){0.f,0.f,0.f,0.f};

  int srow = t >> 2;              // 0..63
  int skc  = (t & 3) * 8;
  for (int kt = 0; kt < K; kt += 32) {
    #pragma unroll
    for (int i = 0; i < 2; i++) {
      int row = srow + i * 64;
      gload_lds16(A + (size_t)(blkM + row) * K + kt + skc, As + (i * 256 + t) * 8);
    }
    gload_lds16(Bt + (size_t)(blkN + srow) * K + kt + skc, Bs + t * 8);
    __syncthreads();
    short8 af[4], bf[2];
    #pragma unroll
    for (int m = 0; m < 4; m++)
      af[m] = *(const short8*)&As[(wr * 64 + m * 16 + l15) * 32 + l4 * 8];
    #pragma unroll
    for (int n = 0; n < 2; n++)
      bf[n] = *(const short8*)&Bs[(wc * 32 + n * 16 + l15) * 32 + l4 * 8];
    #pragma unroll
    for (int m = 0; m < 4; m++)
      #pragma unroll
      for (int n = 0; n < 2; n++)
        acc[m][n] = __builtin_amdgcn_mfma_f32_16x16x32_bf16(af[m], bf[n], acc[m][n], 0, 0, 0);
    __syncthreads();
  }

  int row0 = blkM + wr * 64;
  int col0 = blkN + wc * 32;
  #pragma unroll
  for (int m = 0; m < 4; m++) {
    #pragma unroll
    for (int n = 0; n < 2; n++) {
      int colb = col0 + n * 16 + l15;
      #pragma unroll
      for (int j = 0; j < 4; j++) {
        int row = row0 + m * 16 + l4 * 4 + j;
        out_f[(size_t)row * D_MODEL + colb] = acc[m][n][j] + bias[colb];
      }
    }
  }
}

// -------- flash attention: r10 structure + native exp2 + persistent-zero C --------
// Q [32][2048][64] bf16 (pre-scaled 0.125*log2e), K [32][2048][64] bf16, Vt [32][64][2048] bf16
// O [B][2048][1024] bf16.
// 512 blocks x 512 thr = 2 blocks/CU, 16 waves/CU. Wave w: qh=w>>1, kh=w&1.
// VALU diet v2: (1) EXP2 = __builtin_amdgcn_exp2f -> raw v_exp_f32, compiler-visible
// (hazards tracked; NEVER inline-asm-read MFMA dst -- r8 lesson). Args in [-10,10].
// (2) S-chain seeded from a persistent zero vector zc (C operand) -> kills 16
// v_movs/iter. (3) row-sum via ones-MFMA (r10). Fixed-offset-free softmax:
// P=exp2(S'), normalization (PV)/(P*1) is offset-invariant.
__global__ __launch_bounds__(512, 2) void mha_attn(
    const unsigned short* __restrict__ Q,
    const unsigned short* __restrict__ Kb,
    const unsigned short* __restrict__ Vt,
    unsigned short* __restrict__ O)
{
  const int N = SEQ;
  const int NIT = N / 64;                    // 32
  int id = blockIdx.x;                       // 512 blocks
  int bh    = (id & 7) * 4 + ((id >> 7) & 3);  // 4 heads per XCD
  int qtile = (id >> 3) & 15;                // 16 q-tiles of 128 rows
  int t = threadIdx.x, wv = t >> 6, lane = t & 63;
  int l31 = lane & 31, hi = lane >> 5;
  int kh = wv & 1, qh = wv >> 1;             // key-half, q-group 0..3

  __shared__ __align__(16) unsigned short SMEM[2 * 8192];  // 32KB: per buf {K[4096]|V[4096]}
  __shared__ float CMB[4][64][33];                         // 33.8KB combine scratch

  const unsigned short* Kbh = Kb + (size_t)bh * N * DEPTH;
  const unsigned short* Vbh = Vt + (size_t)bh * DEPTH * N;

  int qrow = qtile * 128 + qh * 32 + l31;
  const unsigned short* Qp = Q + ((size_t)bh * N + qrow) * DEPTH + hi * 8;
  short8 qf[4];
  #pragma unroll
  for (int c = 0; c < 4; c++) qf[c] = *(const short8*)(Qp + c * 16);

  int srow = t >> 3;                         // 0..63
  int sc8  = ((t & 7) ^ (srow & 7)) * 8;     // pre-swizzled source column
  const unsigned short* kst = Kbh + (size_t)srow * DEPTH + sc8;
  const unsigned short* vst = Vbh + (size_t)srow * N + sc8;

  int rbK = (kh * 32 + l31) * 64;
  int rbV0 = l31 * 64, rbV1 = rbV0 + 2048;
  int goQK[4], goPV[2];
  #pragma unroll
  for (int c = 0; c < 4; c++) goQK[c] = ((c * 2 + hi) ^ (l31 & 7)) * 8;
  #pragma unroll
  for (int lc = 0; lc < 2; lc++) goPV[lc] = ((kh * 4 + lc * 2 + hi) ^ (l31 & 7)) * 8;

  short8 ones;
  #pragma unroll
  for (int i = 0; i < 8; i++) ones[i] = (short)0x3F80;   // bf16 1.0

  f32x16 o0, o1, lsacc, zc;
  #pragma unroll
  for (int i = 0; i < 16; i++) { o0[i] = 0.f; o1[i] = 0.f; lsacc[i] = 0.f; zc[i] = 0.f; }

  gload_lds16(kst, SMEM + t * 8);
  gload_lds16(vst, SMEM + 4096 + t * 8);
  asm volatile("s_waitcnt vmcnt(0)" ::: "memory");
  __builtin_amdgcn_sched_barrier(0);
  __builtin_amdgcn_s_barrier();
  __builtin_amdgcn_sched_barrier(0);

#define BODY(BUF, IT)                                                                   \
  do {                                                                                  \
    if ((IT) + 1 < NIT) {                                                               \
      gload_lds16(kst + (size_t)((IT) + 1) * 4096, SMEM + ((BUF) ^ 1) * 8192 + t * 8);  \
      gload_lds16(vst + ((IT) + 1) * 64, SMEM + ((BUF) ^ 1) * 8192 + 4096 + t * 8);     \
    }                                                                                   \
    {                                                                                   \
      const unsigned short* Kc = SMEM + (BUF) * 8192;                                   \
      const unsigned short* Vc = Kc + 4096;                                             \
      __builtin_amdgcn_s_setprio(1);                                                    \
      short8 ka0 = *(const short8*)&Kc[rbK + goQK[0]];                                  \
      f32x16 s = __builtin_amdgcn_mfma_f32_32x32x16_bf16(ka0, qf[0], zc, 0, 0, 0);      \
      _Pragma("unroll") for (int c = 1; c < 4; c++) {                                   \
        short8 ka = *(const short8*)&Kc[rbK + goQK[c]];                                 \
        s = __builtin_amdgcn_mfma_f32_32x32x16_bf16(ka, qf[c], s, 0, 0, 0);             \
      }                                                                                 \
      __builtin_amdgcn_s_setprio(0);                                                    \
      float p[16];                                                                      \
      _Pragma("unroll") for (int r = 0; r < 16; r++) p[r] = EXP2(s[r]);                 \
      _Pragma("unroll") for (int lc = 0; lc < 2; lc++) {                                \
        unsigned int X0 = cvt_pk_bf16(p[8*lc+0], p[8*lc+1]);                            \
        unsigned int X1 = cvt_pk_bf16(p[8*lc+2], p[8*lc+3]);                            \
        unsigned int X2 = cvt_pk_bf16(p[8*lc+4], p[8*lc+5]);                            \
        unsigned int X3 = cvt_pk_bf16(p[8*lc+6], p[8*lc+7]);                            \
        auto r02 = __builtin_amdgcn_permlane32_swap(X0, X2, false, false);              \
        auto r13 = __builtin_amdgcn_permlane32_swap(X1, X3, false, false);              \
        uint4v wvec; wvec[0] = r02[0]; wvec[1] = r13[0]; wvec[2] = r02[1]; wvec[3] = r13[1]; \
        short8 bfrag = __builtin_bit_cast(short8, wvec);                                \
        short8 va = *(const short8*)&Vc[rbV0 + goPV[lc]];                               \
        short8 vb = *(const short8*)&Vc[rbV1 + goPV[lc]];                               \
        __builtin_amdgcn_s_setprio(1);                                                  \
        o0 = __builtin_amdgcn_mfma_f32_32x32x16_bf16(va, bfrag, o0, 0, 0, 0);           \
        o1 = __builtin_amdgcn_mfma_f32_32x32x16_bf16(vb, bfrag, o1, 0, 0, 0);           \
        lsacc = __builtin_amdgcn_mfma_f32_32x32x16_bf16(ones, bfrag, lsacc, 0, 0, 0);   \
        __builtin_amdgcn_s_setprio(0);                                                  \
      }                                                                                 \
    }                                                                                   \
    if ((IT) + 1 < NIT) {                                                               \
      asm volatile("s_waitcnt vmcnt(0)" ::: "memory");                                  \
      __builtin_amdgcn_sched_barrier(0);                                                \
      __builtin_amdgcn_s_barrier();                                                     \
      __builtin_amdgcn_sched_barrier(0);                                                \
    }                                                                                   \
  } while (0)

  for (int it2 = 0; it2 < NIT; it2 += 2) {
    BODY(0, it2);
    BODY(1, it2 + 1);
  }
#undef BODY

  float ls = lsacc[0];   // every acc reg = sum over this wave's key-half (all tiles)

  if (kh == 1) {
    float* c0 = &CMB[qh][lane][0];
    #pragma unroll
    for (int i = 0; i < 16; i++) { c0[i] = o0[i]; c0[16 + i] = o1[i]; }
    c0[32] = ls;
  }
  __syncthreads();
  if (kh == 0) {
    const float* c0 = &CMB[qh][lane][0];
    #pragma unroll
    for (int i = 0; i < 16; i++) { o0[i] += c0[i]; o1[i] += c0[16 + i]; }
    float rl = 1.0f / (ls + c0[32]);

    int b = bh >> 4, h = bh & 15;
    unsigned short* Op = O + ((size_t)b * N + qrow) * D_MODEL + h * DEPTH;
    #pragma unroll
    for (int gq = 0; gq < 4; gq++) {
      #pragma unroll
      for (int rp = 0; rp < 2; rp++) {
        int reg = gq * 4 + rp * 2;
        int d = gq * 8 + hi * 4 + rp * 2;
        *(unsigned int*)(Op + d)      = cvt_pk_bf16(o0[reg] * rl, o0[reg + 1] * rl);
        *(unsigned int*)(Op + 32 + d) = cvt_pk_bf16(o1[reg] * rl, o1[reg + 1] * rl);
      }
    }
  }
}

extern "C" void kernel_launch(void* const* d_in, const int* in_sizes, int n_in,
                              void* d_out, int out_size, void* d_ws, size_t ws_size,
                              hipStream_t stream) {
  const float* x     = (const float*)d_in[0];
  const float* Wqkv  = (const float*)d_in[1];
  const float* bqkv  = (const float*)d_in[2];
  const float* Wproj = (const float*)d_in[3];
  const float* bproj = (const float*)d_in[4];
  float* out = (float*)d_out;

  char* w = (char*)d_ws;
  unsigned short* xb    = (unsigned short*)(w);                       // 8 MB
  unsigned short* wqkT  = (unsigned short*)(w + 8388608);             // 4 MB
  unsigned short* wvT   = (unsigned short*)(w + 8388608 + 4194304);   // 2 MB
  unsigned short* wpT   = (unsigned short*)(w + 8388608 + 4194304 + 2097152);  // 2 MB
  unsigned short* Qbuf  = (unsigned short*)(w + 16777216);            // 8 MB
  unsigned short* Kbuf  = (unsigned short*)(w + 16777216 + 8388608);  // 8 MB
  unsigned short* Vtb   = (unsigned short*)(w + 16777216 + 16777216); // 8 MB
  unsigned short* AOut  = (unsigned short*)(w + 16777216 + 25165824); // 8 MB

  // 1. merged prep (x cvt + Wqkv permute + Wproj transpose)
  mha_prep<<<6144, 256, 0, stream>>>(x, Wqkv, Wproj, xb, wqkT, wvT, wpT);
  // 2. merged QKV gemm (QK part: 512 blocks, V part: 256 blocks) @ 3 blocks/CU
  mha_gemm_qkv<<<768, 256, 0, stream>>>(xb, wqkT, wvT, bqkv, Qbuf, Kbuf, Vtb);
  // 3. flash attention (512 blocks x 512 thr = 2 blocks/CU, 16 waves/CU)
  mha_attn<<<512, 512, 0, stream>>>(Qbuf, Kbuf, Vtb, AOut);
  // 4. projection gemm 128x64 tiles -> fp32 out (512 blocks = 2/CU)
  mha_gemm_proj<<<dim3(16, 32), 256, 0, stream>>>(AOut, wpT, bproj, out);
}

// Round 12
// 111.333 us; speedup vs baseline: 1.3846x; 1.0759x over previous
//
#include <hip/hip_runtime.h>
#include <stdint.h>

#define D_MODEL 1024
#define NHEADS  16
#define DEPTH   64
#define BATCH   2
#define SEQ     2048
#define M_TOK   (BATCH*SEQ)   // 4096

typedef __attribute__((ext_vector_type(8)))  short short8;
typedef __attribute__((ext_vector_type(4)))  float f32x4;
typedef __attribute__((ext_vector_type(16))) float f32x16;
typedef __attribute__((ext_vector_type(4)))  unsigned int uint4v;

#if defined(__has_builtin)
#if __has_builtin(__builtin_amdgcn_exp2f)
#define EXP2(x) __builtin_amdgcn_exp2f(x)
#endif
#endif
#ifndef EXP2
#define EXP2(x) exp2f(x)
#endif

__device__ __forceinline__ unsigned short f2bf(float f) {
  unsigned int u = __float_as_uint(f);
  u += 0x7fffu + ((u >> 16) & 1u);
  return (unsigned short)(u >> 16);
}

__device__ __forceinline__ unsigned int cvt_pk_bf16(float lo, float hi) {
  unsigned int r;
  asm("v_cvt_pk_bf16_f32 %0, %1, %2" : "=v"(r) : "v"(lo), "v"(hi));
  return r;
}

__device__ __forceinline__ void gload_lds16(const unsigned short* g, unsigned short* l) {
  __builtin_amdgcn_global_load_lds((const __attribute__((address_space(1))) void*)g,
                                   (__attribute__((address_space(3))) void*)l, 16, 0, 0);
}

// ------------- merged prep: x->bf16 | Wqkv permute-transpose | Wproj transpose -------------
__global__ void mha_prep(const float* __restrict__ x, const float* __restrict__ Wqkv,
                         const float* __restrict__ Wproj,
                         unsigned short* __restrict__ xb,
                         unsigned short* __restrict__ wqkT,
                         unsigned short* __restrict__ wvT,
                         unsigned short* __restrict__ wpT) {
  __shared__ float tile[32][33];
  int id = blockIdx.x, t = threadIdx.x;
  if (id < 2048) {
    int i = (id * 256 + t) * 8;
    float4 a = *(const float4*)(x + i);
    float4 b = *(const float4*)(x + i + 4);
    uint4 r;
    r.x = (unsigned)f2bf(a.x) | ((unsigned)f2bf(a.y) << 16);
    r.y = (unsigned)f2bf(a.z) | ((unsigned)f2bf(a.w) << 16);
    r.z = (unsigned)f2bf(b.x) | ((unsigned)f2bf(b.y) << 16);
    r.w = (unsigned)f2bf(b.z) | ((unsigned)f2bf(b.w) << 16);
    *(uint4*)(xb + i) = r;
  } else if (id < 5120) {
    int b = id - 2048;
    int c0 = (b % 96) * 32, k0 = (b / 96) * 32;
    int tx = t & 31, ty = t >> 5;
    for (int i = ty; i < 32; i += 8)
      tile[i][tx] = Wqkv[(size_t)(k0 + i) * 3072 + c0 + tx];
    __syncthreads();
    for (int i = ty; i < 32; i += 8) {
      int c = c0 + i;
      int hd = c / 3;
      int s = c - hd * 3;
      unsigned short v = f2bf(tile[tx][i]);
      if (s < 2) wqkT[(size_t)(s * 1024 + hd) * 1024 + k0 + tx] = v;
      else       wvT [(size_t)hd * 1024 + k0 + tx] = v;
    }
  } else {
    int b = id - 5120;
    int c0 = (b & 31) * 32, k0 = (b >> 5) * 32;
    int tx = t & 31, ty = t >> 5;
    for (int i = ty; i < 32; i += 8)
      tile[i][tx] = Wproj[(size_t)(k0 + i) * 1024 + c0 + tx];
    __syncthreads();
    for (int i = ty; i < 32; i += 8)
      wpT[(size_t)(c0 + i) * 1024 + k0 + tx] = f2bf(tile[tx][i]);
  }
}

// ------------- merged QKV gemm, BK=64 + XOR-swizzled LDS + XCD-mapped QK blocks -------------
// QK part (blocks [0,512)): XCD x owns A-stripes [4x,4x+4) x all 16 B-panels ->
// per-XCD working set = 1MB A + 4MB B (fits L2) vs ~8.5MB round-robin.
// BK=64: 16 K-iters (2 barriers each) with 32 MFMAs between -> barrier cost halved.
// LDS granule XOR-swizzle (slot g holds global granule g^(row&7), read back same
// involution): per-octet lanes cover all 8 positions -> conflict-free at 128B rows.
__global__ __launch_bounds__(256, 3) void mha_gemm_qkv(
    const unsigned short* __restrict__ xb,
    const unsigned short* __restrict__ wqkT,
    const unsigned short* __restrict__ wvT,
    const float* __restrict__ bias,
    unsigned short* __restrict__ Qb,
    unsigned short* __restrict__ Kb,
    unsigned short* __restrict__ Vtb)
{
  __shared__ __align__(16) unsigned short As[128 * 64];   // 16KB
  __shared__ __align__(16) unsigned short Bs[128 * 64];   // 16KB
  const int K = 1024;
  int id = blockIdx.x;
  bool m0 = id < 512;
  int bx, by, bz = 0;
  const unsigned short *A, *Bt;
  if (m0) {
    int xcd = id & 7, idx = id >> 3;
    by = xcd * 4 + (idx >> 4);     // 4 A-stripes per XCD
    bx = idx & 15;
    A = xb; Bt = wqkT;
  } else {
    int b2 = id - 512;
    bx = b2 & 15; by = (b2 >> 4) & 7; bz = b2 >> 7;
    A = wvT; Bt = xb + (size_t)bz * SEQ * D_MODEL;
  }
  int t = threadIdx.x;
  int wv = t >> 6, lane = t & 63;
  int l15 = lane & 15, l4 = lane >> 4;
  int wr = wv >> 1, wc = wv & 1;
  int blkM = by * 128, blkN = bx * 128;

  f32x4 acc[4][4];
  for (int m = 0; m < 4; m++) for (int n = 0; n < 4; n++) acc[m][n] = (f32x4){0.f,0.f,0.f,0.f};

  for (int kt = 0; kt < K; kt += 64) {
    #pragma unroll
    for (int i = 0; i < 4; i++) {
      int e = i * 256 + t;
      int row = e >> 3;
      int sc = ((e & 7) ^ (row & 7)) * 8;   // pre-swizzled source granule
      gload_lds16(A  + (size_t)(blkM + row) * K + kt + sc, As + e * 8);
      gload_lds16(Bt + (size_t)(blkN + row) * K + kt + sc, Bs + e * 8);
    }
    __syncthreads();
    #pragma unroll
    for (int kk = 0; kk < 2; kk++) {
      int gp = ((kk * 4 + l4) ^ (l15 & 7)) * 8;   // swizzled read slot (row&7 == l15&7)
      short8 af[4], bf[4];
      #pragma unroll
      for (int m = 0; m < 4; m++)
        af[m] = *(const short8*)&As[(wr * 64 + m * 16 + l15) * 64 + gp];
      #pragma unroll
      for (int n = 0; n < 4; n++)
        bf[n] = *(const short8*)&Bs[(wc * 64 + n * 16 + l15) * 64 + gp];
      #pragma unroll
      for (int m = 0; m < 4; m++)
        #pragma unroll
        for (int n = 0; n < 4; n++)
          acc[m][n] = __builtin_amdgcn_mfma_f32_16x16x32_bf16(af[m], bf[n], acc[m][n], 0, 0, 0);
    }
    __syncthreads();
  }

  int row0 = blkM + wr * 64;
  int col0 = blkN + wc * 64;
  #pragma unroll
  for (int m = 0; m < 4; m++) {
    #pragma unroll
    for (int n = 0; n < 4; n++) {
      int colb = col0 + n * 16 + l15;
      #pragma unroll
      for (int j = 0; j < 4; j++) {
        int row = row0 + m * 16 + l4 * 4 + j;
        float v = acc[m][n][j];
        if (m0) {
          int s = colb >> 10, hd = colb & 1023;
          v += bias[hd * 3 + s];
          if (s == 0) v *= 0.18033688011112042f;  // (1/8)*log2(e): softmax scale + exp2 base
          size_t idx = ((size_t)((row >> 11) * NHEADS + (hd >> 6)) * SEQ + (row & 2047)) * DEPTH + (hd & 63);
          (s == 0 ? Qb : Kb)[idx] = f2bf(v);
        } else {
          v += bias[row * 3 + 2];
          Vtb[((size_t)(bz * 1024 + row)) * SEQ + colb] = f2bf(v);
        }
      }
    }
  }
}

// ---------------- proj gemm (fp32 out): 128x64 tiles, BK=64 swizzled, XCD-mapped ----------------
__global__ __launch_bounds__(256, 3) void mha_gemm_proj(
    const unsigned short* __restrict__ A,
    const unsigned short* __restrict__ Bt,
    const float* __restrict__ bias,
    float* __restrict__ out_f)
{
  __shared__ __align__(16) unsigned short As[128 * 64];   // 16KB
  __shared__ __align__(16) unsigned short Bs[64 * 64];    // 8KB
  const int K = 1024;
  int id = blockIdx.x;                 // 512 blocks
  int xcd = id & 7, idx = id >> 3;
  int by = xcd * 4 + (idx >> 4);       // 0..31
  int bx = idx & 15;                   // 0..15 (64-col panels)
  int t = threadIdx.x;
  int wv = t >> 6, lane = t & 63;
  int l15 = lane & 15, l4 = lane >> 4;
  int wr = wv >> 1, wc = wv & 1;
  int blkM = by * 128, blkN = bx * 64;

  f32x4 acc[4][2];
  for (int m = 0; m < 4; m++) for (int n = 0; n < 2; n++) acc[m][n] = (f32x4){0.f,0.f,0.f,0.f};

  for (int kt = 0; kt < K; kt += 64) {
    #pragma unroll
    for (int i = 0; i < 4; i++) {
      int e = i * 256 + t;
      int row = e >> 3;
      int sc = ((e & 7) ^ (row & 7)) * 8;
      gload_lds16(A + (size_t)(blkM + row) * K + kt + sc, As + e * 8);
    }
    #pragma unroll
    for (int i = 0; i < 2; i++) {
      int e = i * 256 + t;
      int row = e >> 3;
      int sc = ((e & 7) ^ (row & 7)) * 8;
      gload_lds16(Bt + (size_t)(blkN + row) * K + kt + sc, Bs + e * 8);
    }
    __syncthreads();
    #pragma unroll
    for (int kk = 0; kk < 2; kk++) {
      int gp = ((kk * 4 + l4) ^ (l15 & 7)) * 8;
      short8 af[4], bf[2];
      #pragma unroll
      for (int m = 0; m < 4; m++)
        af[m] = *(const short8*)&As[(wr * 64 + m * 16 + l15) * 64 + gp];
      #pragma unroll
      for (int n = 0; n < 2; n++)
        bf[n] = *(const short8*)&Bs[(wc * 32 + n * 16 + l15) * 64 + gp];
      #pragma unroll
      for (int m = 0; m < 4; m++)
        #pragma unroll
        for (int n = 0; n < 2; n++)
          acc[m][n] = __builtin_amdgcn_mfma_f32_16x16x32_bf16(af[m], bf[n], acc[m][n], 0, 0, 0);
    }
    __syncthreads();
  }

  int row0 = blkM + wr * 64;
  int col0 = blkN + wc * 32;
  #pragma unroll
  for (int m = 0; m < 4; m++) {
    #pragma unroll
    for (int n = 0; n < 2; n++) {
      int colb = col0 + n * 16 + l15;
      #pragma unroll
      for (int j = 0; j < 4; j++) {
        int row = row0 + m * 16 + l4 * 4 + j;
        out_f[(size_t)row * D_MODEL + colb] = acc[m][n][j] + bias[colb];
      }
    }
  }
}

// -------- flash attention: r11 (frozen this round) --------
__global__ __launch_bounds__(512, 2) void mha_attn(
    const unsigned short* __restrict__ Q,
    const unsigned short* __restrict__ Kb,
    const unsigned short* __restrict__ Vt,
    unsigned short* __restrict__ O)
{
  const int N = SEQ;
  const int NIT = N / 64;                    // 32
  int id = blockIdx.x;                       // 512 blocks
  int bh    = (id & 7) * 4 + ((id >> 7) & 3);  // 4 heads per XCD
  int qtile = (id >> 3) & 15;                // 16 q-tiles of 128 rows
  int t = threadIdx.x, wv = t >> 6, lane = t & 63;
  int l31 = lane & 31, hi = lane >> 5;
  int kh = wv & 1, qh = wv >> 1;             // key-half, q-group 0..3

  __shared__ __align__(16) unsigned short SMEM[2 * 8192];  // 32KB: per buf {K[4096]|V[4096]}
  __shared__ float CMB[4][64][33];                         // 33.8KB combine scratch

  const unsigned short* Kbh = Kb + (size_t)bh * N * DEPTH;
  const unsigned short* Vbh = Vt + (size_t)bh * DEPTH * N;

  int qrow = qtile * 128 + qh * 32 + l31;
  const unsigned short* Qp = Q + ((size_t)bh * N + qrow) * DEPTH + hi * 8;
  short8 qf[4];
  #pragma unroll
  for (int c = 0; c < 4; c++) qf[c] = *(const short8*)(Qp + c * 16);

  int srow = t >> 3;                         // 0..63
  int sc8  = ((t & 7) ^ (srow & 7)) * 8;     // pre-swizzled source column
  const unsigned short* kst = Kbh + (size_t)srow * DEPTH + sc8;
  const unsigned short* vst = Vbh + (size_t)srow * N + sc8;

  int rbK = (kh * 32 + l31) * 64;
  int rbV0 = l31 * 64, rbV1 = rbV0 + 2048;
  int goQK[4], goPV[2];
  #pragma unroll
  for (int c = 0; c < 4; c++) goQK[c] = ((c * 2 + hi) ^ (l31 & 7)) * 8;
  #pragma unroll
  for (int lc = 0; lc < 2; lc++) goPV[lc] = ((kh * 4 + lc * 2 + hi) ^ (l31 & 7)) * 8;

  short8 ones;
  #pragma unroll
  for (int i = 0; i < 8; i++) ones[i] = (short)0x3F80;   // bf16 1.0

  f32x16 o0, o1, lsacc, zc;
  #pragma unroll
  for (int i = 0; i < 16; i++) { o0[i] = 0.f; o1[i] = 0.f; lsacc[i] = 0.f; zc[i] = 0.f; }

  gload_lds16(kst, SMEM + t * 8);
  gload_lds16(vst, SMEM + 4096 + t * 8);
  asm volatile("s_waitcnt vmcnt(0)" ::: "memory");
  __builtin_amdgcn_sched_barrier(0);
  __builtin_amdgcn_s_barrier();
  __builtin_amdgcn_sched_barrier(0);

#define BODY(BUF, IT)                                                                   \
  do {                                                                                  \
    if ((IT) + 1 < NIT) {                                                               \
      gload_lds16(kst + (size_t)((IT) + 1) * 4096, SMEM + ((BUF) ^ 1) * 8192 + t * 8);  \
      gload_lds16(vst + ((IT) + 1) * 64, SMEM + ((BUF) ^ 1) * 8192 + 4096 + t * 8);     \
    }                                                                                   \
    {                                                                                   \
      const unsigned short* Kc = SMEM + (BUF) * 8192;                                   \
      const unsigned short* Vc = Kc + 4096;                                             \
      __builtin_amdgcn_s_setprio(1);                                                    \
      short8 ka0 = *(const short8*)&Kc[rbK + goQK[0]];                                  \
      f32x16 s = __builtin_amdgcn_mfma_f32_32x32x16_bf16(ka0, qf[0], zc, 0, 0, 0);      \
      _Pragma("unroll") for (int c = 1; c < 4; c++) {                                   \
        short8 ka = *(const short8*)&Kc[rbK + goQK[c]];                                 \
        s = __builtin_amdgcn_mfma_f32_32x32x16_bf16(ka, qf[c], s, 0, 0, 0);             \
      }                                                                                 \
      __builtin_amdgcn_s_setprio(0);                                                    \
      float p[16];                                                                      \
      _Pragma("unroll") for (int r = 0; r < 16; r++) p[r] = EXP2(s[r]);                 \
      _Pragma("unroll") for (int lc = 0; lc < 2; lc++) {                                \
        unsigned int X0 = cvt_pk_bf16(p[8*lc+0], p[8*lc+1]);                            \
        unsigned int X1 = cvt_pk_bf16(p[8*lc+2], p[8*lc+3]);                            \
        unsigned int X2 = cvt_pk_bf16(p[8*lc+4], p[8*lc+5]);                            \
        unsigned int X3 = cvt_pk_bf16(p[8*lc+6], p[8*lc+7]);                            \
        auto r02 = __builtin_amdgcn_permlane32_swap(X0, X2, false, false);              \
        auto r13 = __builtin_amdgcn_permlane32_swap(X1, X3, false, false);              \
        uint4v wvec; wvec[0] = r02[0]; wvec[1] = r13[0]; wvec[2] = r02[1]; wvec[3] = r13[1]; \
        short8 bfrag = __builtin_bit_cast(short8, wvec);                                \
        short8 va = *(const short8*)&Vc[rbV0 + goPV[lc]];                               \
        short8 vb = *(const short8*)&Vc[rbV1 + goPV[lc]];                               \
        __builtin_amdgcn_s_setprio(1);                                                  \
        o0 = __builtin_amdgcn_mfma_f32_32x32x16_bf16(va, bfrag, o0, 0, 0, 0);           \
        o1 = __builtin_amdgcn_mfma_f32_32x32x16_bf16(vb, bfrag, o1, 0, 0, 0);           \
        lsacc = __builtin_amdgcn_mfma_f32_32x32x16_bf16(ones, bfrag, lsacc, 0, 0, 0);   \
        __builtin_amdgcn_s_setprio(0);                                                  \
      }                                                                                 \
    }                                                                                   \
    if ((IT) + 1 < NIT) {                                                               \
      asm volatile("s_waitcnt vmcnt(0)" ::: "memory");                                  \
      __builtin_amdgcn_sched_barrier(0);                                                \
      __builtin_amdgcn_s_barrier();                                                     \
      __builtin_amdgcn_sched_barrier(0);                                                \
    }                                                                                   \
  } while (0)

  for (int it2 = 0; it2 < NIT; it2 += 2) {
    BODY(0, it2);
    BODY(1, it2 + 1);
  }
#undef BODY

  float ls = lsacc[0];   // every acc reg = sum over this wave's key-half (all tiles)

  if (kh == 1) {
    float* c0 = &CMB[qh][lane][0];
    #pragma unroll
    for (int i = 0; i < 16; i++) { c0[i] = o0[i]; c0[16 + i] = o1[i]; }
    c0[32] = ls;
  }
  __syncthreads();
  if (kh == 0) {
    const float* c0 = &CMB[qh][lane][0];
    #pragma unroll
    for (int i = 0; i < 16; i++) { o0[i] += c0[i]; o1[i] += c0[16 + i]; }
    float rl = 1.0f / (ls + c0[32]);

    int b = bh >> 4, h = bh & 15;
    unsigned short* Op = O + ((size_t)b * N + qrow) * D_MODEL + h * DEPTH;
    #pragma unroll
    for (int gq = 0; gq < 4; gq++) {
      #pragma unroll
      for (int rp = 0; rp < 2; rp++) {
        int reg = gq * 4 + rp * 2;
        int d = gq * 8 + hi * 4 + rp * 2;
        *(unsigned int*)(Op + d)      = cvt_pk_bf16(o0[reg] * rl, o0[reg + 1] * rl);
        *(unsigned int*)(Op + 32 + d) = cvt_pk_bf16(o1[reg] * rl, o1[reg + 1] * rl);
      }
    }
  }
}

extern "C" void kernel_launch(void* const* d_in, const int* in_sizes, int n_in,
                              void* d_out, int out_size, void* d_ws, size_t ws_size,
                              hipStream_t stream) {
  const float* x     = (const float*)d_in[0];
  const float* Wqkv  = (const float*)d_in[1];
  const float* bqkv  = (const float*)d_in[2];
  const float* Wproj = (const float*)d_in[3];
  const float* bproj = (const float*)d_in[4];
  float* out = (float*)d_out;

  char* w = (char*)d_ws;
  unsigned short* xb    = (unsigned short*)(w);                       // 8 MB
  unsigned short* wqkT  = (unsigned short*)(w + 8388608);             // 4 MB
  unsigned short* wvT   = (unsigned short*)(w + 8388608 + 4194304);   // 2 MB
  unsigned short* wpT   = (unsigned short*)(w + 8388608 + 4194304 + 2097152);  // 2 MB
  unsigned short* Qbuf  = (unsigned short*)(w + 16777216);            // 8 MB
  unsigned short* Kbuf  = (unsigned short*)(w + 16777216 + 8388608);  // 8 MB
  unsigned short* Vtb   = (unsigned short*)(w + 16777216 + 16777216); // 8 MB
  unsigned short* AOut  = (unsigned short*)(w + 16777216 + 25165824); // 8 MB

  // 1. merged prep (x cvt + Wqkv permute + Wproj transpose)
  mha_prep<<<6144, 256, 0, stream>>>(x, Wqkv, Wproj, xb, wqkT, wvT, wpT);
  // 2. merged QKV gemm (QK: 512 blocks XCD-mapped, V: 256 blocks), BK=64
  mha_gemm_qkv<<<768, 256, 0, stream>>>(xb, wqkT, wvT, bqkv, Qbuf, Kbuf, Vtb);
  // 3. flash attention (512 blocks x 512 thr, frozen r11)
  mha_attn<<<512, 512, 0, stream>>>(Qbuf, Kbuf, Vtb, AOut);
  // 4. projection gemm 128x64 tiles, BK=64, XCD-mapped -> fp32 out
  mha_gemm_proj<<<512, 256, 0, stream>>>(AOut, wpT, bproj, out);
}

// Round 13
// 110.817 us; speedup vs baseline: 1.3910x; 1.0047x over previous
//
#include <hip/hip_runtime.h>
#include <stdint.h>

#define D_MODEL 1024
#define NHEADS  16
#define DEPTH   64
#define BATCH   2
#define SEQ     2048
#define M_TOK   (BATCH*SEQ)   // 4096

typedef __attribute__((ext_vector_type(8)))  short short8;
typedef __attribute__((ext_vector_type(4)))  float f32x4;
typedef __attribute__((ext_vector_type(16))) float f32x16;
typedef __attribute__((ext_vector_type(4)))  unsigned int uint4v;

#if defined(__has_builtin)
#if __has_builtin(__builtin_amdgcn_exp2f)
#define EXP2(x) __builtin_amdgcn_exp2f(x)
#endif
#endif
#ifndef EXP2
#define EXP2(x) exp2f(x)
#endif

__device__ __forceinline__ unsigned short f2bf(float f) {
  unsigned int u = __float_as_uint(f);
  u += 0x7fffu + ((u >> 16) & 1u);
  return (unsigned short)(u >> 16);
}

__device__ __forceinline__ unsigned int cvt_pk_bf16(float lo, float hi) {
  unsigned int r;
  asm("v_cvt_pk_bf16_f32 %0, %1, %2" : "=v"(r) : "v"(lo), "v"(hi));
  return r;
}

__device__ __forceinline__ void gload_lds16(const unsigned short* g, unsigned short* l) {
  __builtin_amdgcn_global_load_lds((const __attribute__((address_space(1))) void*)g,
                                   (__attribute__((address_space(3))) void*)l, 16, 0, 0);
}

// ------------- merged prep: x->bf16 | Wqkv permute-transpose | Wproj transpose -------------
__global__ void mha_prep(const float* __restrict__ x, const float* __restrict__ Wqkv,
                         const float* __restrict__ Wproj,
                         unsigned short* __restrict__ xb,
                         unsigned short* __restrict__ wqkT,
                         unsigned short* __restrict__ wvT,
                         unsigned short* __restrict__ wpT) {
  __shared__ float tile[32][33];
  int id = blockIdx.x, t = threadIdx.x;
  if (id < 2048) {
    int i = (id * 256 + t) * 8;
    float4 a = *(const float4*)(x + i);
    float4 b = *(const float4*)(x + i + 4);
    uint4 r;
    r.x = (unsigned)f2bf(a.x) | ((unsigned)f2bf(a.y) << 16);
    r.y = (unsigned)f2bf(a.z) | ((unsigned)f2bf(a.w) << 16);
    r.z = (unsigned)f2bf(b.x) | ((unsigned)f2bf(b.y) << 16);
    r.w = (unsigned)f2bf(b.z) | ((unsigned)f2bf(b.w) << 16);
    *(uint4*)(xb + i) = r;
  } else if (id < 5120) {
    int b = id - 2048;
    int c0 = (b % 96) * 32, k0 = (b / 96) * 32;
    int tx = t & 31, ty = t >> 5;
    for (int i = ty; i < 32; i += 8)
      tile[i][tx] = Wqkv[(size_t)(k0 + i) * 3072 + c0 + tx];
    __syncthreads();
    for (int i = ty; i < 32; i += 8) {
      int c = c0 + i;
      int hd = c / 3;
      int s = c - hd * 3;
      unsigned short v = f2bf(tile[tx][i]);
      if (s < 2) wqkT[(size_t)(s * 1024 + hd) * 1024 + k0 + tx] = v;
      else       wvT [(size_t)hd * 1024 + k0 + tx] = v;
    }
  } else {
    int b = id - 5120;
    int c0 = (b & 31) * 32, k0 = (b >> 5) * 32;
    int tx = t & 31, ty = t >> 5;
    for (int i = ty; i < 32; i += 8)
      tile[i][tx] = Wproj[(size_t)(k0 + i) * 1024 + c0 + tx];
    __syncthreads();
    for (int i = ty; i < 32; i += 8)
      wpT[(size_t)(c0 + i) * 1024 + k0 + tx] = f2bf(tile[tx][i]);
  }
}

// ------------- merged QKV gemm, BK=64 + XOR-swizzled LDS + XCD-mapped QK blocks -------------
__global__ __launch_bounds__(256, 3) void mha_gemm_qkv(
    const unsigned short* __restrict__ xb,
    const unsigned short* __restrict__ wqkT,
    const unsigned short* __restrict__ wvT,
    const float* __restrict__ bias,
    unsigned short* __restrict__ Qb,
    unsigned short* __restrict__ Kb,
    unsigned short* __restrict__ Vtb)
{
  __shared__ __align__(16) unsigned short As[128 * 64];   // 16KB
  __shared__ __align__(16) unsigned short Bs[128 * 64];   // 16KB
  const int K = 1024;
  int id = blockIdx.x;
  bool m0 = id < 512;
  int bx, by, bz = 0;
  const unsigned short *A, *Bt;
  if (m0) {
    int xcd = id & 7, idx = id >> 3;
    by = xcd * 4 + (idx >> 4);     // 4 A-stripes per XCD
    bx = idx & 15;
    A = xb; Bt = wqkT;
  } else {
    int b2 = id - 512;
    bx = b2 & 15; by = (b2 >> 4) & 7; bz = b2 >> 7;
    A = wvT; Bt = xb + (size_t)bz * SEQ * D_MODEL;
  }
  int t = threadIdx.x;
  int wv = t >> 6, lane = t & 63;
  int l15 = lane & 15, l4 = lane >> 4;
  int wr = wv >> 1, wc = wv & 1;
  int blkM = by * 128, blkN = bx * 128;

  f32x4 acc[4][4];
  for (int m = 0; m < 4; m++) for (int n = 0; n < 4; n++) acc[m][n] = (f32x4){0.f,0.f,0.f,0.f};

  for (int kt = 0; kt < K; kt += 64) {
    #pragma unroll
    for (int i = 0; i < 4; i++) {
      int e = i * 256 + t;
      int row = e >> 3;
      int sc = ((e & 7) ^ (row & 7)) * 8;   // pre-swizzled source granule
      gload_lds16(A  + (size_t)(blkM + row) * K + kt + sc, As + e * 8);
      gload_lds16(Bt + (size_t)(blkN + row) * K + kt + sc, Bs + e * 8);
    }
    __syncthreads();
    #pragma unroll
    for (int kk = 0; kk < 2; kk++) {
      int gp = ((kk * 4 + l4) ^ (l15 & 7)) * 8;   // swizzled read slot (row&7 == l15&7)
      short8 af[4], bf[4];
      #pragma unroll
      for (int m = 0; m < 4; m++)
        af[m] = *(const short8*)&As[(wr * 64 + m * 16 + l15) * 64 + gp];
      #pragma unroll
      for (int n = 0; n < 4; n++)
        bf[n] = *(const short8*)&Bs[(wc * 64 + n * 16 + l15) * 64 + gp];
      #pragma unroll
      for (int m = 0; m < 4; m++)
        #pragma unroll
        for (int n = 0; n < 4; n++)
          acc[m][n] = __builtin_amdgcn_mfma_f32_16x16x32_bf16(af[m], bf[n], acc[m][n], 0, 0, 0);
    }
    __syncthreads();
  }

  int row0 = blkM + wr * 64;
  int col0 = blkN + wc * 64;
  #pragma unroll
  for (int m = 0; m < 4; m++) {
    #pragma unroll
    for (int n = 0; n < 4; n++) {
      int colb = col0 + n * 16 + l15;
      #pragma unroll
      for (int j = 0; j < 4; j++) {
        int row = row0 + m * 16 + l4 * 4 + j;
        float v = acc[m][n][j];
        if (m0) {
          int s = colb >> 10, hd = colb & 1023;
          v += bias[hd * 3 + s];
          if (s == 0) v *= 0.18033688011112042f;  // (1/8)*log2(e): softmax scale + exp2 base
          size_t idx = ((size_t)((row >> 11) * NHEADS + (hd >> 6)) * SEQ + (row & 2047)) * DEPTH + (hd & 63);
          (s == 0 ? Qb : Kb)[idx] = f2bf(v);
        } else {
          v += bias[row * 3 + 2];
          Vtb[((size_t)(bz * 1024 + row)) * SEQ + colb] = f2bf(v);
        }
      }
    }
  }
}

// ---------------- proj gemm (fp32 out): 128x64 tiles, BK=64 swizzled, XCD-mapped ----------------
__global__ __launch_bounds__(256, 3) void mha_gemm_proj(
    const unsigned short* __restrict__ A,
    const unsigned short* __restrict__ Bt,
    const float* __restrict__ bias,
    float* __restrict__ out_f)
{
  __shared__ __align__(16) unsigned short As[128 * 64];   // 16KB
  __shared__ __align__(16) unsigned short Bs[64 * 64];    // 8KB
  const int K = 1024;
  int id = blockIdx.x;                 // 512 blocks
  int xcd = id & 7, idx = id >> 3;
  int by = xcd * 4 + (idx >> 4);       // 0..31
  int bx = idx & 15;                   // 0..15 (64-col panels)
  int t = threadIdx.x;
  int wv = t >> 6, lane = t & 63;
  int l15 = lane & 15, l4 = lane >> 4;
  int wr = wv >> 1, wc = wv & 1;
  int blkM = by * 128, blkN = bx * 64;

  f32x4 acc[4][2];
  for (int m = 0; m < 4; m++) for (int n = 0; n < 2; n++) acc[m][n] = (f32x4){0.f,0.f,0.f,0.f};

  for (int kt = 0; kt < K; kt += 64) {
    #pragma unroll
    for (int i = 0; i < 4; i++) {
      int e = i * 256 + t;
      int row = e >> 3;
      int sc = ((e & 7) ^ (row & 7)) * 8;
      gload_lds16(A + (size_t)(blkM + row) * K + kt + sc, As + e * 8);
    }
    #pragma unroll
    for (int i = 0; i < 2; i++) {
      int e = i * 256 + t;
      int row = e >> 3;
      int sc = ((e & 7) ^ (row & 7)) * 8;
      gload_lds16(Bt + (size_t)(blkN + row) * K + kt + sc, Bs + e * 8);
    }
    __syncthreads();
    #pragma unroll
    for (int kk = 0; kk < 2; kk++) {
      int gp = ((kk * 4 + l4) ^ (l15 & 7)) * 8;
      short8 af[4], bf[2];
      #pragma unroll
      for (int m = 0; m < 4; m++)
        af[m] = *(const short8*)&As[(wr * 64 + m * 16 + l15) * 64 + gp];
      #pragma unroll
      for (int n = 0; n < 2; n++)
        bf[n] = *(const short8*)&Bs[(wc * 32 + n * 16 + l15) * 64 + gp];
      #pragma unroll
      for (int m = 0; m < 4; m++)
        #pragma unroll
        for (int n = 0; n < 2; n++)
          acc[m][n] = __builtin_amdgcn_mfma_f32_16x16x32_bf16(af[m], bf[n], acc[m][n], 0, 0, 0);
    }
    __syncthreads();
  }

  int row0 = blkM + wr * 64;
  int col0 = blkN + wc * 32;
  #pragma unroll
  for (int m = 0; m < 4; m++) {
    #pragma unroll
    for (int n = 0; n < 2; n++) {
      int colb = col0 + n * 16 + l15;
      #pragma unroll
      for (int j = 0; j < 4; j++) {
        int row = row0 + m * 16 + l4 * 4 + j;
        out_f[(size_t)row * D_MODEL + colb] = acc[m][n][j] + bias[colb];
      }
    }
  }
}

// -------- flash attention: KVBLK=128, two 32-key groups per wave per barrier section --------
// Q [32][2048][64] bf16 (pre-scaled 0.125*log2e), K [32][2048][64] bf16, Vt [32][64][2048] bf16
// O [B][2048][1024] bf16.
// r12 pipe audit: MFMA 38% + VALU 33% + LDS-read 45% ~= wall -> pipes near-serial because
// per-iter barriers convoy all 16 waves/CU into the same phase. Fix: stage 128 keys/tile
// (K[128][64] + V[64][128] = 32KB/buf, 2 bufs = 64KB; combine scratch OVERLAID on SMEM
// after the loop -> still 2 blocks/CU = 16 waves). NIT 32->16: barrier+drain events
// halved; each barrier section = 2 independent 32-key groups (20 MFMA) so group-0 PV
// overlaps group-1 QK. Wave w: qh=w>>1 (32 of 128 q-rows), kh=w&1 (64-key half).
// Swizzle: same XOR-granule involution; V rows now 16 granules (4-bit idx, xor low-3).
__global__ __launch_bounds__(512, 2) void mha_attn(
    const unsigned short* __restrict__ Q,
    const unsigned short* __restrict__ Kb,
    const unsigned short* __restrict__ Vt,
    unsigned short* __restrict__ O)
{
  const int N = SEQ;
  const int NIT = N / 128;                   // 16
  int id = blockIdx.x;                       // 512 blocks
  int bh    = (id & 7) * 4 + ((id >> 7) & 3);  // 4 heads per XCD
  int qtile = (id >> 3) & 15;                // 16 q-tiles of 128 rows
  int t = threadIdx.x, wv = t >> 6, lane = t & 63;
  int l31 = lane & 31, hi = lane >> 5;
  int kh = wv & 1, qh = wv >> 1;             // key-half (64 keys), q-group 0..3

  // 64KB: per buf {K[128][64] @0 | V[64][128] @8192 elems}; combine scratch overlaid after loop
  __shared__ __align__(16) unsigned short SMEM[2 * 16384];

  const unsigned short* Kbh = Kb + (size_t)bh * N * DEPTH;
  const unsigned short* Vbh = Vt + (size_t)bh * DEPTH * N;

  int qrow = qtile * 128 + qh * 32 + l31;
  const unsigned short* Qp = Q + ((size_t)bh * N + qrow) * DEPTH + hi * 8;
  short8 qf[4];
  #pragma unroll
  for (int c = 0; c < 4; c++) qf[c] = *(const short8*)(Qp + c * 16);

  // staging: thread t stages K granules {t, t+512} and V granules {t, t+512}
  int krow = t >> 3;                              // 0..63 (K rows 64..127 via +4096 elem offset)
  int ksc  = ((t & 7) ^ (krow & 7)) * 8;          // (krow+64)&7 == krow&7 -> same swizzle
  const unsigned short* kst = Kbh + (size_t)krow * DEPTH + ksc;
  int vrow = t >> 4;                              // 0..31 (V rows 32..63 via +32*N offset)
  int vg   = t & 15;
  int vsc  = ((vg ^ (vrow & 7))) * 8;             // (vrow+32)&7 == vrow&7
  const unsigned short* vst = Vbh + (size_t)vrow * N + vsc;

  // swizzled LDS reads: K tile row r (64-elem rows), V tile row r (128-elem rows)
  int rbK0 = (kh * 64 + l31) * 64;                // group0 key rows; group1: +2048
  int rbV0 = l31 * 128, rbV1 = rbV0 + 4096;       // V rows l31 / l31+32
  int goQK[4], goPV[4];
  #pragma unroll
  for (int c = 0; c < 4; c++) goQK[c] = ((c * 2 + hi) ^ (l31 & 7)) * 8;
  #pragma unroll
  for (int i = 0; i < 4; i++) {                   // i = g*2+lc
    int g = i >> 1, lc = i & 1;
    goPV[i] = ((kh * 8 + g * 4 + lc * 2 + hi) ^ (l31 & 7)) * 8;
  }

  short8 ones;
  #pragma unroll
  for (int i = 0; i < 8; i++) ones[i] = (short)0x3F80;   // bf16 1.0

  f32x16 o0, o1, lsacc, zc;
  #pragma unroll
  for (int i = 0; i < 16; i++) { o0[i] = 0.f; o1[i] = 0.f; lsacc[i] = 0.f; zc[i] = 0.f; }

  // prologue: stage tile 0 into buf 0 (4 gloads/thread)
  gload_lds16(kst,                       SMEM + t * 8);
  gload_lds16(kst + 4096,                SMEM + 4096 + t * 8);
  gload_lds16(vst,                       SMEM + 8192 + t * 8);
  gload_lds16(vst + (size_t)32 * N,      SMEM + 12288 + t * 8);
  asm volatile("s_waitcnt vmcnt(0)" ::: "memory");
  __builtin_amdgcn_sched_barrier(0);
  __builtin_amdgcn_s_barrier();
  __builtin_amdgcn_sched_barrier(0);

#define BODY(BUF, IT)                                                                     \
  do {                                                                                    \
    if ((IT) + 1 < NIT) {                                                                 \
      unsigned short* nb = SMEM + ((BUF) ^ 1) * 16384;                                    \
      const unsigned short* kn = kst + (size_t)((IT) + 1) * 8192;                         \
      const unsigned short* vn = vst + ((IT) + 1) * 128;                                  \
      gload_lds16(kn,                  nb + t * 8);                                       \
      gload_lds16(kn + 4096,           nb + 4096 + t * 8);                                \
      gload_lds16(vn,                  nb + 8192 + t * 8);                                \
      gload_lds16(vn + (size_t)32 * N, nb + 12288 + t * 8);                               \
    }                                                                                     \
    {                                                                                     \
      const unsigned short* Kc = SMEM + (BUF) * 16384;                                    \
      const unsigned short* Vc = Kc + 8192;                                               \
      _Pragma("unroll") for (int g = 0; g < 2; g++) {                                     \
        __builtin_amdgcn_s_setprio(1);                                                    \
        short8 ka0 = *(const short8*)&Kc[rbK0 + g * 2048 + goQK[0]];                      \
        f32x16 s = __builtin_amdgcn_mfma_f32_32x32x16_bf16(ka0, qf[0], zc, 0, 0, 0);      \
        _Pragma("unroll") for (int c = 1; c < 4; c++) {                                   \
          short8 ka = *(const short8*)&Kc[rbK0 + g * 2048 + goQK[c]];                     \
          s = __builtin_amdgcn_mfma_f32_32x32x16_bf16(ka, qf[c], s, 0, 0, 0);             \
        }                                                                                 \
        __builtin_amdgcn_s_setprio(0);                                                    \
        float p[16];                                                                      \
        _Pragma("unroll") for (int r = 0; r < 16; r++) p[r] = EXP2(s[r]);                 \
        _Pragma("unroll") for (int lc = 0; lc < 2; lc++) {                                \
          unsigned int X0 = cvt_pk_bf16(p[8*lc+0], p[8*lc+1]);                            \
          unsigned int X1 = cvt_pk_bf16(p[8*lc+2], p[8*lc+3]);                            \
          unsigned int X2 = cvt_pk_bf16(p[8*lc+4], p[8*lc+5]);                            \
          unsigned int X3 = cvt_pk_bf16(p[8*lc+6], p[8*lc+7]);                            \
          auto r02 = __builtin_amdgcn_permlane32_swap(X0, X2, false, false);              \
          auto r13 = __builtin_amdgcn_permlane32_swap(X1, X3, false, false);              \
          uint4v wvec; wvec[0] = r02[0]; wvec[1] = r13[0]; wvec[2] = r02[1]; wvec[3] = r13[1]; \
          short8 bfrag = __builtin_bit_cast(short8, wvec);                                \
          short8 va = *(const short8*)&Vc[rbV0 + goPV[g * 2 + lc]];                       \
          short8 vb = *(const short8*)&Vc[rbV1 + goPV[g * 2 + lc]];                       \
          __builtin_amdgcn_s_setprio(1);                                                  \
          o0 = __builtin_amdgcn_mfma_f32_32x32x16_bf16(va, bfrag, o0, 0, 0, 0);           \
          o1 = __builtin_amdgcn_mfma_f32_32x32x16_bf16(vb, bfrag, o1, 0, 0, 0);           \
          lsacc = __builtin_amdgcn_mfma_f32_32x32x16_bf16(ones, bfrag, lsacc, 0, 0, 0);   \
          __builtin_amdgcn_s_setprio(0);                                                  \
        }                                                                                 \
      }                                                                                   \
    }                                                                                     \
    if ((IT) + 1 < NIT) {                                                                 \
      asm volatile("s_waitcnt vmcnt(0)" ::: "memory");                                    \
      __builtin_amdgcn_sched_barrier(0);                                                  \
      __builtin_amdgcn_s_barrier();                                                       \
      __builtin_amdgcn_sched_barrier(0);                                                  \
    }                                                                                     \
  } while (0)

  for (int it2 = 0; it2 < NIT; it2 += 2) {
    BODY(0, it2);
    BODY(1, it2 + 1);
  }
#undef BODY

  float ls = lsacc[0];   // every acc reg = sum over this wave's key-half (all tiles)

  // ---- combine key-split partials (kh 0/1) via scratch overlaid on SMEM (loop done) ----
  __syncthreads();                                 // everyone done reading K/V tiles
  float* cmb = (float*)SMEM;                       // 4 slots x 64 x 33 = 33.8KB <= 64KB
  if (kh == 1) {
    float* c0 = cmb + (qh * 64 + lane) * 33;
    #pragma unroll
    for (int i = 0; i < 16; i++) { c0[i] = o0[i]; c0[16 + i] = o1[i]; }
    c0[32] = ls;
  }
  __syncthreads();
  if (kh == 0) {
    const float* c0 = cmb + (qh * 64 + lane) * 33;
    #pragma unroll
    for (int i = 0; i < 16; i++) { o0[i] += c0[i]; o1[i] += c0[16 + i]; }
    float rl = 1.0f / (ls + c0[32]);

    int b = bh >> 4, h = bh & 15;
    unsigned short* Op = O + ((size_t)b * N + qrow) * D_MODEL + h * DEPTH;
    // acc layout: col q = l31, row d = (reg&3) + 8*(reg>>2) + 4*hi (+32 for o1)
    #pragma unroll
    for (int gq = 0; gq < 4; gq++) {
      #pragma unroll
      for (int rp = 0; rp < 2; rp++) {
        int reg = gq * 4 + rp * 2;
        int d = gq * 8 + hi * 4 + rp * 2;
        *(unsigned int*)(Op + d)      = cvt_pk_bf16(o0[reg] * rl, o0[reg + 1] * rl);
        *(unsigned int*)(Op + 32 + d) = cvt_pk_bf16(o1[reg] * rl, o1[reg + 1] * rl);
      }
    }
  }
}

extern "C" void kernel_launch(void* const* d_in, const int* in_sizes, int n_in,
                              void* d_out, int out_size, void* d_ws, size_t ws_size,
                              hipStream_t stream) {
  const float* x     = (const float*)d_in[0];
  const float* Wqkv  = (const float*)d_in[1];
  const float* bqkv  = (const float*)d_in[2];
  const float* Wproj = (const float*)d_in[3];
  const float* bproj = (const float*)d_in[4];
  float* out = (float*)d_out;

  char* w = (char*)d_ws;
  unsigned short* xb    = (unsigned short*)(w);                       // 8 MB
  unsigned short* wqkT  = (unsigned short*)(w + 8388608);             // 4 MB
  unsigned short* wvT   = (unsigned short*)(w + 8388608 + 4194304);   // 2 MB
  unsigned short* wpT   = (unsigned short*)(w + 8388608 + 4194304 + 2097152);  // 2 MB
  unsigned short* Qbuf  = (unsigned short*)(w + 16777216);            // 8 MB
  unsigned short* Kbuf  = (unsigned short*)(w + 16777216 + 8388608);  // 8 MB
  unsigned short* Vtb   = (unsigned short*)(w + 16777216 + 16777216); // 8 MB
  unsigned short* AOut  = (unsigned short*)(w + 16777216 + 25165824); // 8 MB

  // 1. merged prep (x cvt + Wqkv permute + Wproj transpose)
  mha_prep<<<6144, 256, 0, stream>>>(x, Wqkv, Wproj, xb, wqkT, wvT, wpT);
  // 2. merged QKV gemm (QK: 512 blocks XCD-mapped, V: 256 blocks), BK=64
  mha_gemm_qkv<<<768, 256, 0, stream>>>(xb, wqkT, wvT, bqkv, Qbuf, Kbuf, Vtb);
  // 3. flash attention (512 blocks x 512 thr, KVBLK=128, 2 blocks/CU)
  mha_attn<<<512, 512, 0, stream>>>(Qbuf, Kbuf, Vtb, AOut);
  // 4. projection gemm 128x64 tiles, BK=64, XCD-mapped -> fp32 out
  mha_gemm_proj<<<512, 256, 0, stream>>>(AOut, wpT, bproj, out);
}